// Round 9
// baseline (418.726 us; speedup 1.0000x reference)
//
#include <hip/hip_runtime.h>
#include <float.h>

#define HC 128   // H*C
#define NH 4     // heads
#define PSLICES 8
#define SEG 2048 // elements per scan block

__device__ __forceinline__ float lrelu(float v){ return v > 0.f ? v : 0.2f*v; }

__device__ __forceinline__ unsigned short f2bf(float f){   // round-to-nearest-even
  unsigned int u = __float_as_uint(f);
  unsigned int r = (u + 0x7fffu + ((u >> 16) & 1u)) >> 16;
  return (unsigned short)r;
}

// ---------------- CSR build (counting sort of edges by dst, self-loops appended) ----------------
__global__ void k_deg(const int* __restrict__ ei, int* __restrict__ cnt, int E, int N){
  int total = E + N;
  for (int i = blockIdx.x*blockDim.x + threadIdx.x; i < total; i += gridDim.x*blockDim.x){
    int d = (i < E) ? ei[E + i] : (i - E);
    atomicAdd(&cnt[d], 1);
  }
}

// ---- device-wide exclusive scan of cnt[0..N) -> rowptr[0..N], 3 dispatches ----
__global__ void k_part(const int* __restrict__ cnt, int* __restrict__ bsum, int N){
  __shared__ int red[4];
  int b = blockIdx.x, t = threadIdx.x;
  int base = b*SEG;
  int s = 0;
  #pragma unroll
  for (int j = 0; j < 8; ++j){
    int idx = base + t + j*256;          // coalesced
    if (idx < N) s += cnt[idx];
  }
  for (int d = 32; d; d >>= 1) s += __shfl_down(s, d);
  if ((t & 63) == 0) red[t >> 6] = s;
  __syncthreads();
  if (t == 0) bsum[b] = red[0] + red[1] + red[2] + red[3];
}

__global__ void k_scanb(const int* __restrict__ bsum, int* __restrict__ ebsum,
                        int* __restrict__ rowptrN, int nb){
  __shared__ int part[256];
  int t = threadIdx.x;
  int own = (t < nb) ? bsum[t] : 0;
  part[t] = own;
  __syncthreads();
  for (int off = 1; off < 256; off <<= 1){
    int v = (t >= off) ? part[t-off] : 0;
    __syncthreads();
    part[t] += v;
    __syncthreads();
  }
  if (t < nb) ebsum[t] = part[t] - own;    // exclusive prefix of block sums
  if (t == 255) *rowptrN = part[255];      // grand total
}

__global__ void k_final(const int* __restrict__ cnt, const int* __restrict__ ebsum,
                        int* __restrict__ rowptr, int N){
  __shared__ int part[256];
  int b = blockIdx.x, t = threadIdx.x;
  int base = b*SEG + t*8;
  int v[8]; int s = 0;
  #pragma unroll
  for (int j = 0; j < 8; ++j){
    int idx = base + j;
    v[j] = (idx < N) ? cnt[idx] : 0;
    s += v[j];
  }
  part[t] = s;
  __syncthreads();
  for (int off = 1; off < 256; off <<= 1){
    int pv = (t >= off) ? part[t-off] : 0;
    __syncthreads();
    part[t] += pv;
    __syncthreads();
  }
  int pre = ebsum[b] + part[t] - s;        // exclusive prefix for this thread's run
  #pragma unroll
  for (int j = 0; j < 8; ++j){
    int idx = base + j;
    if (idx < N) rowptr[idx] = pre;
    pre += v[j];
  }
}

__global__ void k_scatter(const int* __restrict__ ei, const int* __restrict__ rowptr,
                          int* __restrict__ fill, int* __restrict__ srcs, int E, int N){
  int total = E + N;
  for (int i = blockIdx.x*blockDim.x + threadIdx.x; i < total; i += gridDim.x*blockDim.x){
    int s, d;
    if (i < E){ s = ei[i]; d = ei[E + i]; } else { s = d = i - E; }
    int slot = rowptr[d] + atomicAdd(&fill[d], 1);
    srcs[slot] = s;
  }
}

// ---------------- LDS-tiled GEMM (X[N,K] @ W[K,128]) fused with attention reductions ----------
// Output H stored as bf16 (consumed only by the alpha-weighted gather in k_agg).
template<int K>
__global__ __launch_bounds__(256) void k_gemm_att(
    const float* __restrict__ X, const float* __restrict__ W,
    const float* __restrict__ as_, const float* __restrict__ ad_,
    unsigned short* __restrict__ Hb, float* __restrict__ asrc, float* __restrict__ adst,
    int n)
{
  __shared__ float Ws[64][64];     // [k][c] chunk
  __shared__ float Xs[64][68];     // [row][k] chunk, padded
  int tid = threadIdx.x;
  int tx = tid & 15;               // 16 col-groups of float4 -> 64 cols
  int ty = tid >> 4;               // 16 row-groups
  int row0 = blockIdx.x * 64;
  int cbase = blockIdx.y * 64;

  float4 acc[4];
  #pragma unroll
  for (int i = 0; i < 4; ++i) acc[i] = make_float4(0.f,0.f,0.f,0.f);

  for (int kc = 0; kc < K; kc += 64){
    #pragma unroll
    for (int p = 0; p < 4; ++p){
      int idx = tid + 256*p;
      int rr = idx >> 4, kk = (idx & 15) * 4;
      float4 w = *reinterpret_cast<const float4*>(W + (size_t)(kc + rr)*HC + cbase + kk);
      *reinterpret_cast<float4*>(&Ws[rr][kk]) = w;
    }
    #pragma unroll
    for (int p = 0; p < 4; ++p){
      int idx = tid + 256*p;
      int rr = idx >> 4, kk = (idx & 15) * 4;
      int g = row0 + rr;
      float4 v = make_float4(0.f,0.f,0.f,0.f);
      if (g < n) v = *reinterpret_cast<const float4*>(X + (size_t)g*K + kc + kk);
      *reinterpret_cast<float4*>(&Xs[rr][kk]) = v;
    }
    __syncthreads();
    #pragma unroll 4
    for (int k = 0; k < 64; ++k){
      float4 w = *reinterpret_cast<const float4*>(&Ws[k][tx*4]);
      #pragma unroll
      for (int i = 0; i < 4; ++i){
        float xv = Xs[ty + 16*i][k];
        acc[i].x += xv*w.x; acc[i].y += xv*w.y; acc[i].z += xv*w.z; acc[i].w += xv*w.w;
      }
    }
    __syncthreads();
  }

  int c0 = cbase + tx*4;
  int hd = c0 >> 5;
  float4 a4 = *reinterpret_cast<const float4*>(as_ + c0);
  float4 d4 = *reinterpret_cast<const float4*>(ad_ + c0);
  #pragma unroll
  for (int i = 0; i < 4; ++i){
    int row = row0 + ty + 16*i;
    float ps = acc[i].x*a4.x + acc[i].y*a4.y + acc[i].z*a4.z + acc[i].w*a4.w;
    float pd = acc[i].x*d4.x + acc[i].y*d4.y + acc[i].z*d4.z + acc[i].w*d4.w;
    ps += __shfl_down(ps, 4); pd += __shfl_down(pd, 4);
    ps += __shfl_down(ps, 2); pd += __shfl_down(pd, 2);
    ps += __shfl_down(ps, 1); pd += __shfl_down(pd, 1);
    if (row < n){
      uint2 pk;
      pk.x = (unsigned int)f2bf(acc[i].x) | ((unsigned int)f2bf(acc[i].y) << 16);
      pk.y = (unsigned int)f2bf(acc[i].z) | ((unsigned int)f2bf(acc[i].w) << 16);
      *reinterpret_cast<uint2*>(Hb + (size_t)row*HC + c0) = pk;
      if ((tx & 7) == 0){
        asrc[row*NH + hd] = ps;
        adst[row*NH + hd] = pd;
      }
    }
  }
}

// ---------------- per-edge attention weights (numerator of softmax, f32x4 per slot) ----------
// One wave per node; lane j handles CSR slot base+j. Writes are fully coalesced (16B/lane).
__global__ void k_alpha(const float* __restrict__ asrc, const float* __restrict__ adst,
                        const int* __restrict__ rowptr, const int* __restrict__ srcs,
                        float* __restrict__ alpha, int n)
{
  int lane = threadIdx.x & 63;
  int node = blockIdx.x*4 + (threadIdx.x >> 6);
  if (node >= n) return;
  int base = __builtin_amdgcn_readfirstlane(rowptr[node]);
  int deg  = __builtin_amdgcn_readfirstlane(rowptr[node+1]) - base;
  float4 ad = *reinterpret_cast<const float4*>(adst + node*NH);
  for (int j = lane; j < deg; j += 64){
    int s = srcs[base + j];
    float4 as = *reinterpret_cast<const float4*>(asrc + s*NH);
    float4 a;
    a.x = __expf(lrelu(as.x + ad.x));
    a.y = __expf(lrelu(as.y + ad.y));
    a.z = __expf(lrelu(as.z + ad.z));
    a.w = __expf(lrelu(as.w + ad.w));
    *reinterpret_cast<float4*>(alpha + (size_t)(base + j)*NH) = a;
  }
}

// ---------------- weighted gather-aggregate: 2 waves per node, 2 edges per iteration -------
// wave = (node, channel-half): 32 lanes x 2 channels, lane-parity handles alternate edges.
// Denominator accumulated in-register from the streamed alpha values.
__global__ void k_agg(const unsigned short* __restrict__ Xh, const float* __restrict__ alpha,
                      const int* __restrict__ rowptr, const int* __restrict__ srcs,
                      const float* __restrict__ bias,
                      float* __restrict__ out, int n, int do_relu)
{
  int wid  = threadIdx.x >> 6;            // 0..3
  int lane = threadIdx.x & 63;
  int node = blockIdx.x*2 + (wid >> 1);
  int half = wid & 1;
  if (node >= n) return;
  int base = __builtin_amdgcn_readfirstlane(rowptr[node]);
  int deg  = __builtin_amdgcn_readfirstlane(rowptr[node+1]) - base;
  int par = lane >> 5;                    // edge parity
  int l5  = lane & 31;
  int hd  = half*2 + (l5 >> 4);           // global head for this lane's channels
  int c0  = half*64 + l5*2;               // 2 channels per lane
  float accx = 0.f, accy = 0.f, wsum = 0.f;
  int niter = (deg + 1) >> 1;
  for (int t = 0; t < niter; ++t){
    int j = 2*t + par;
    bool ok = j < deg;
    int slot = base + (ok ? j : 0);
    float w = ok ? alpha[(size_t)slot*NH + hd] : 0.f;
    int s = srcs[slot];
    unsigned int u = *reinterpret_cast<const unsigned int*>(Xh + (size_t)s*HC + c0);
    float vx = __uint_as_float(u << 16);
    float vy = __uint_as_float(u & 0xffff0000u);
    wsum += w; accx += w*vx; accy += w*vy;
  }
  accx += __shfl_xor(accx, 32);
  accy += __shfl_xor(accy, 32);
  wsum += __shfl_xor(wsum, 32);
  if (par == 0){
    float inv = 1.f / wsum;
    float ox = accx*inv + bias[c0];
    float oy = accy*inv + bias[c0+1];
    if (do_relu){ ox = fmaxf(ox, 0.f); oy = fmaxf(oy, 0.f); }
    *reinterpret_cast<float2*>(out + (size_t)node*HC + c0) = make_float2(ox, oy);
  }
}

// ---------------- pooling: group boundaries (batch is sorted) ----------------
__global__ void k_bounds(const int* __restrict__ batch, int* __restrict__ start, int N, int G){
  for (int i = blockIdx.x*blockDim.x + threadIdx.x; i <= N; i += gridDim.x*blockDim.x){
    int b  = (i < N) ? batch[i]   : G;
    int bp = (i > 0) ? batch[i-1] : -1;
    for (int g = bp + 1; g <= b; ++g) if (g <= G) start[g] = i;
  }
}

__global__ void k_pool_partial(const float* __restrict__ h2, const int* __restrict__ start,
                               float* __restrict__ psum, float* __restrict__ pmax, int G){
  int g = blockIdx.x / PSLICES, s = blockIdx.x % PSLICES;
  int c = threadIdx.x;   // 128 threads
  int st = start[g], en = start[g+1];
  float sm = 0.f, mx = -FLT_MAX;
  for (int i = st + s; i < en; i += PSLICES){
    float v = h2[(size_t)i*HC + c];
    sm += v; mx = fmaxf(mx, v);
  }
  psum[(g*PSLICES+s)*HC + c] = sm;
  pmax[(g*PSLICES+s)*HC + c] = mx;
}

// ---------------- final: reduce partials, normalize, two MLP heads ----------------
__global__ void k_head(const float* __restrict__ psum, const float* __restrict__ pmax,
                       const int* __restrict__ start,
                       const float* __restrict__ cW1, const float* __restrict__ cb1,
                       const float* __restrict__ cWo, const float* __restrict__ cbo,
                       const float* __restrict__ dW1, const float* __restrict__ db1,
                       const float* __restrict__ dWo, const float* __restrict__ dbo,
                       float* __restrict__ out, int G){
  __shared__ float feat[256];
  __shared__ float hid[128];
  __shared__ float red[2];
  int g = blockIdx.x;
  int t = threadIdx.x;   // 128
  int cnt = start[g+1] - start[g];
  float sm = 0.f, mx = -FLT_MAX;
  for (int s = 0; s < PSLICES; ++s){
    sm += psum[(g*PSLICES+s)*HC + t];
    mx = fmaxf(mx, pmax[(g*PSLICES+s)*HC + t]);
  }
  float mean = sm / (float)((cnt > 1) ? cnt : 1);
  feat[t] = mean; feat[128 + t] = mx;
  float sq = mean*mean + mx*mx;
  for (int d = 32; d; d >>= 1) sq += __shfl_xor(sq, d);
  if ((t & 63) == 0) red[t >> 6] = sq;
  __syncthreads();
  float norm = sqrtf(red[0] + red[1]);
  float scale = 1.f / fmaxf(norm, 1e-12f);
  feat[t] *= scale; feat[128 + t] *= scale;
  __syncthreads();
  float hsum = cb1[t];
  for (int k = 0; k < 256; ++k) hsum += feat[k]*cW1[k*128 + t];
  hid[t] = fmaxf(hsum, 0.f);
  __syncthreads();
  if (t < 8){
    float o = cbo[t];
    for (int k = 0; k < 128; ++k) o += hid[k]*cWo[k*8 + t];
    out[g*8 + t] = o;
  }
  __syncthreads();
  float dsum = db1[t];
  for (int k = 0; k < 256; ++k) dsum += feat[k]*dW1[k*128 + t];
  hid[t] = fmaxf(dsum, 0.f);
  __syncthreads();
  if (t < 3){
    float o = dbo[t];
    for (int k = 0; k < 128; ++k) o += hid[k]*dWo[k*3 + t];
    out[G*8 + g*3 + t] = o;
  }
}

extern "C" void kernel_launch(void* const* d_in, const int* in_sizes, int n_in,
                              void* d_out, int out_size, void* d_ws, size_t ws_size,
                              hipStream_t stream) {
  const float* x     = (const float*)d_in[0];
  const int*   ei    = (const int*)  d_in[1];
  const int*   batch = (const int*)  d_in[2];
  const float* eW1 = (const float*)d_in[4];
  const float* eas1= (const float*)d_in[5];
  const float* ead1= (const float*)d_in[6];
  const float* eb1 = (const float*)d_in[7];
  const float* eW2 = (const float*)d_in[8];
  const float* eas2= (const float*)d_in[9];
  const float* ead2= (const float*)d_in[10];
  const float* eb2 = (const float*)d_in[11];
  const float* cW1 = (const float*)d_in[12];
  const float* cb1 = (const float*)d_in[13];
  const float* cWo = (const float*)d_in[14];
  const float* cbo = (const float*)d_in[15];
  const float* dW1 = (const float*)d_in[16];
  const float* db1 = (const float*)d_in[17];
  const float* dWo = (const float*)d_in[18];
  const float* dbo = (const float*)d_in[19];

  const int N = in_sizes[0] / 64;
  const int E = in_sizes[1] / 2;
  const int G = 64;

  char* ws = (char*)d_ws;
  size_t off = 0;
  auto alloc = [&](size_t bytes)->void* {
    void* p = ws + off; off += (bytes + 255) & ~(size_t)255; return p;
  };
  int*   rowptr = (int*)  alloc((size_t)(N+1)*4);
  int*   cnt    = (int*)  alloc((size_t)N*4);
  int*   srcs   = (int*)  alloc((size_t)(E+N)*4);
  float* asrc   = (float*)alloc((size_t)N*NH*4);
  float* adst   = (float*)alloc((size_t)N*NH*4);
  unsigned short* bufH = (unsigned short*)alloc((size_t)N*HC*2);  // bf16 gather matrix
  float* bufB   = (float*)alloc((size_t)N*HC*4);
  float* alpha  = (float*)alloc((size_t)(E+N)*NH*4);              // per-slot softmax numerators
  int*   startg = (int*)  alloc((size_t)(G+1)*4);
  float* psum   = (float*)alloc((size_t)G*PSLICES*HC*4);
  float* pmax   = (float*)alloc((size_t)G*PSLICES*HC*4);
  int*   bsum   = (int*)  alloc((size_t)256*4);
  int*   ebsum  = (int*)  alloc((size_t)256*4);
  (void)ws_size; (void)n_in; (void)out_size;

  int total = E + N;
  int egrid = (total + 255) / 256; if (egrid > 4096) egrid = 4096;

  hipMemsetAsync(cnt, 0, (size_t)N*4, stream);
  k_deg<<<egrid, 256, 0, stream>>>(ei, cnt, E, N);
  int nb = (N + SEG - 1) / SEG;              // 25 blocks at N=50000 (<=256 supported)
  k_part <<<nb, 256, 0, stream>>>(cnt, bsum, N);
  k_scanb<<<1,  256, 0, stream>>>(bsum, ebsum, rowptr + N, nb);
  k_final<<<nb, 256, 0, stream>>>(cnt, ebsum, rowptr, N);
  hipMemsetAsync(cnt, 0, (size_t)N*4, stream);
  k_scatter<<<egrid, 256, 0, stream>>>(ei, rowptr, cnt, srcs, E, N);

  dim3 ggrid((N + 63) / 64, 2);
  int agrid = (N + 3) / 4;
  int ggrid2 = (N + 1) / 2;
  // layer 1: h1 = relu(GAT(x) + b1)
  k_gemm_att<64><<<ggrid, 256, 0, stream>>>(x, eW1, eas1, ead1, bufH, asrc, adst, N);
  k_alpha<<<agrid, 256, 0, stream>>>(asrc, adst, rowptr, srcs, alpha, N);
  k_agg<<<ggrid2, 256, 0, stream>>>(bufH, alpha, rowptr, srcs, eb1, bufB, N, 1);
  // layer 2: h2 = GAT(h1) + b2
  k_gemm_att<128><<<ggrid, 256, 0, stream>>>(bufB, eW2, eas2, ead2, bufH, asrc, adst, N);
  k_alpha<<<agrid, 256, 0, stream>>>(asrc, adst, rowptr, srcs, alpha, N);
  k_agg<<<ggrid2, 256, 0, stream>>>(bufH, alpha, rowptr, srcs, eb2, bufB, N, 0);

  // pooling + heads
  k_bounds<<<64, 256, 0, stream>>>(batch, startg, N, G);
  k_pool_partial<<<G*PSLICES, 128, 0, stream>>>(bufB, startg, psum, pmax, G);
  k_head<<<G, 128, 0, stream>>>(psum, pmax, startg, cW1, cb1, cWo, cbo,
                                dW1, db1, dWo, dbo, (float*)d_out, G);
}

// Round 10
// 280.104 us; speedup vs baseline: 1.4949x; 1.4949x over previous
//
#include <hip/hip_runtime.h>
#include <float.h>

#define HC 128   // H*C
#define NH 4     // heads
#define PSLICES 8
#define SEG 2048 // elements per scan block

__device__ __forceinline__ float lrelu(float v){ return v > 0.f ? v : 0.2f*v; }

__device__ __forceinline__ unsigned short f2bf(float f){   // round-to-nearest-even
  unsigned int u = __float_as_uint(f);
  unsigned int r = (u + 0x7fffu + ((u >> 16) & 1u)) >> 16;
  return (unsigned short)r;
}

// ---------------- CSR build (counting sort of edges by dst, self-loops appended) ----------------
__global__ void k_deg(const int* __restrict__ ei, int* __restrict__ cnt, int E, int N){
  int total = E + N;
  for (int i = blockIdx.x*blockDim.x + threadIdx.x; i < total; i += gridDim.x*blockDim.x){
    int d = (i < E) ? ei[E + i] : (i - E);
    atomicAdd(&cnt[d], 1);
  }
}

// ---- device-wide exclusive scan of cnt[0..N) -> rowptr[0..N], 3 dispatches ----
__global__ void k_part(const int* __restrict__ cnt, int* __restrict__ bsum, int N){
  __shared__ int red[4];
  int b = blockIdx.x, t = threadIdx.x;
  int base = b*SEG;
  int s = 0;
  #pragma unroll
  for (int j = 0; j < 8; ++j){
    int idx = base + t + j*256;          // coalesced
    if (idx < N) s += cnt[idx];
  }
  for (int d = 32; d; d >>= 1) s += __shfl_down(s, d);
  if ((t & 63) == 0) red[t >> 6] = s;
  __syncthreads();
  if (t == 0) bsum[b] = red[0] + red[1] + red[2] + red[3];
}

__global__ void k_scanb(const int* __restrict__ bsum, int* __restrict__ ebsum,
                        int* __restrict__ rowptrN, int nb){
  __shared__ int part[256];
  int t = threadIdx.x;
  int own = (t < nb) ? bsum[t] : 0;
  part[t] = own;
  __syncthreads();
  for (int off = 1; off < 256; off <<= 1){
    int v = (t >= off) ? part[t-off] : 0;
    __syncthreads();
    part[t] += v;
    __syncthreads();
  }
  if (t < nb) ebsum[t] = part[t] - own;    // exclusive prefix of block sums
  if (t == 255) *rowptrN = part[255];      // grand total
}

__global__ void k_final(const int* __restrict__ cnt, const int* __restrict__ ebsum,
                        int* __restrict__ rowptr, int N){
  __shared__ int part[256];
  int b = blockIdx.x, t = threadIdx.x;
  int base = b*SEG + t*8;
  int v[8]; int s = 0;
  #pragma unroll
  for (int j = 0; j < 8; ++j){
    int idx = base + j;
    v[j] = (idx < N) ? cnt[idx] : 0;
    s += v[j];
  }
  part[t] = s;
  __syncthreads();
  for (int off = 1; off < 256; off <<= 1){
    int pv = (t >= off) ? part[t-off] : 0;
    __syncthreads();
    part[t] += pv;
    __syncthreads();
  }
  int pre = ebsum[b] + part[t] - s;        // exclusive prefix for this thread's run
  #pragma unroll
  for (int j = 0; j < 8; ++j){
    int idx = base + j;
    if (idx < N) rowptr[idx] = pre;
    pre += v[j];
  }
}

__global__ void k_scatter(const int* __restrict__ ei, const int* __restrict__ rowptr,
                          int* __restrict__ fill, int* __restrict__ srcs, int E, int N){
  int total = E + N;
  for (int i = blockIdx.x*blockDim.x + threadIdx.x; i < total; i += gridDim.x*blockDim.x){
    int s, d;
    if (i < E){ s = ei[i]; d = ei[E + i]; } else { s = d = i - E; }
    int slot = rowptr[d] + atomicAdd(&fill[d], 1);
    srcs[slot] = s;
  }
}

// ---------------- LDS-tiled GEMM (X[N,K] @ W[K,128]) fused with attention reductions ----------
// Output H stored as bf16 (consumed only by the alpha-weighted gather in k_agg).
template<int K>
__global__ __launch_bounds__(256) void k_gemm_att(
    const float* __restrict__ X, const float* __restrict__ W,
    const float* __restrict__ as_, const float* __restrict__ ad_,
    unsigned short* __restrict__ Hb, float* __restrict__ asrc, float* __restrict__ adst,
    int n)
{
  __shared__ float Ws[64][64];     // [k][c] chunk
  __shared__ float Xs[64][68];     // [row][k] chunk, padded
  int tid = threadIdx.x;
  int tx = tid & 15;               // 16 col-groups of float4 -> 64 cols
  int ty = tid >> 4;               // 16 row-groups
  int row0 = blockIdx.x * 64;
  int cbase = blockIdx.y * 64;

  float4 acc[4];
  #pragma unroll
  for (int i = 0; i < 4; ++i) acc[i] = make_float4(0.f,0.f,0.f,0.f);

  for (int kc = 0; kc < K; kc += 64){
    #pragma unroll
    for (int p = 0; p < 4; ++p){
      int idx = tid + 256*p;
      int rr = idx >> 4, kk = (idx & 15) * 4;
      float4 w = *reinterpret_cast<const float4*>(W + (size_t)(kc + rr)*HC + cbase + kk);
      *reinterpret_cast<float4*>(&Ws[rr][kk]) = w;
    }
    #pragma unroll
    for (int p = 0; p < 4; ++p){
      int idx = tid + 256*p;
      int rr = idx >> 4, kk = (idx & 15) * 4;
      int g = row0 + rr;
      float4 v = make_float4(0.f,0.f,0.f,0.f);
      if (g < n) v = *reinterpret_cast<const float4*>(X + (size_t)g*K + kc + kk);
      *reinterpret_cast<float4*>(&Xs[rr][kk]) = v;
    }
    __syncthreads();
    #pragma unroll 4
    for (int k = 0; k < 64; ++k){
      float4 w = *reinterpret_cast<const float4*>(&Ws[k][tx*4]);
      #pragma unroll
      for (int i = 0; i < 4; ++i){
        float xv = Xs[ty + 16*i][k];
        acc[i].x += xv*w.x; acc[i].y += xv*w.y; acc[i].z += xv*w.z; acc[i].w += xv*w.w;
      }
    }
    __syncthreads();
  }

  int c0 = cbase + tx*4;
  int hd = c0 >> 5;
  float4 a4 = *reinterpret_cast<const float4*>(as_ + c0);
  float4 d4 = *reinterpret_cast<const float4*>(ad_ + c0);
  #pragma unroll
  for (int i = 0; i < 4; ++i){
    int row = row0 + ty + 16*i;
    float ps = acc[i].x*a4.x + acc[i].y*a4.y + acc[i].z*a4.z + acc[i].w*a4.w;
    float pd = acc[i].x*d4.x + acc[i].y*d4.y + acc[i].z*d4.z + acc[i].w*d4.w;
    ps += __shfl_down(ps, 4); pd += __shfl_down(pd, 4);
    ps += __shfl_down(ps, 2); pd += __shfl_down(pd, 2);
    ps += __shfl_down(ps, 1); pd += __shfl_down(pd, 1);
    if (row < n){
      uint2 pk;
      pk.x = (unsigned int)f2bf(acc[i].x) | ((unsigned int)f2bf(acc[i].y) << 16);
      pk.y = (unsigned int)f2bf(acc[i].z) | ((unsigned int)f2bf(acc[i].w) << 16);
      *reinterpret_cast<uint2*>(Hb + (size_t)row*HC + c0) = pk;
      if ((tx & 7) == 0){
        asrc[row*NH + hd] = ps;
        adst[row*NH + hd] = pd;
      }
    }
  }
}

// ---------------- fused edge softmax + aggregation: one wave per node, 4-edge unroll -------
// softmax without max-subtraction (scores are O(1) by construction: weights ~0.05):
// out = (sum_j exp(e_j) * h[src_j]) / (sum_j exp(e_j))  ==  reference softmax exactly.
// 4 independent row-gathers issued per iteration for memory-level parallelism.
__global__ void k_agg(const unsigned short* __restrict__ Xh, const float* __restrict__ asrc,
                      const float* __restrict__ adst, const int* __restrict__ rowptr,
                      const int* __restrict__ srcs, const float* __restrict__ bias,
                      float* __restrict__ out, int n, int do_relu)
{
  int lane = threadIdx.x & 63;
  int node = blockIdx.x*4 + (threadIdx.x >> 6);
  if (node >= n) return;
  int base = __builtin_amdgcn_readfirstlane(rowptr[node]);
  int deg  = __builtin_amdgcn_readfirstlane(rowptr[node+1]) - base;
  int hd = lane >> 4;                       // head for this lane's channels
  float adh = adst[node*NH + hd];
  int c0 = lane*2;                          // 2 channels per lane
  float accx = 0.f, accy = 0.f, wsum = 0.f;
  int j = 0;
  for (; j + 4 <= deg; j += 4){
    int s0 = __builtin_amdgcn_readfirstlane(srcs[base + j]);
    int s1 = __builtin_amdgcn_readfirstlane(srcs[base + j + 1]);
    int s2 = __builtin_amdgcn_readfirstlane(srcs[base + j + 2]);
    int s3 = __builtin_amdgcn_readfirstlane(srcs[base + j + 3]);
    unsigned int u0 = *reinterpret_cast<const unsigned int*>(Xh + (size_t)s0*HC + c0);
    unsigned int u1 = *reinterpret_cast<const unsigned int*>(Xh + (size_t)s1*HC + c0);
    unsigned int u2 = *reinterpret_cast<const unsigned int*>(Xh + (size_t)s2*HC + c0);
    unsigned int u3 = *reinterpret_cast<const unsigned int*>(Xh + (size_t)s3*HC + c0);
    float a0 = asrc[s0*NH + hd];
    float a1 = asrc[s1*NH + hd];
    float a2 = asrc[s2*NH + hd];
    float a3 = asrc[s3*NH + hd];
    float w0 = __expf(lrelu(a0 + adh));
    float w1 = __expf(lrelu(a1 + adh));
    float w2 = __expf(lrelu(a2 + adh));
    float w3 = __expf(lrelu(a3 + adh));
    wsum += (w0 + w1) + (w2 + w3);
    accx += w0*__uint_as_float(u0 << 16) + w1*__uint_as_float(u1 << 16)
          + w2*__uint_as_float(u2 << 16) + w3*__uint_as_float(u3 << 16);
    accy += w0*__uint_as_float(u0 & 0xffff0000u) + w1*__uint_as_float(u1 & 0xffff0000u)
          + w2*__uint_as_float(u2 & 0xffff0000u) + w3*__uint_as_float(u3 & 0xffff0000u);
  }
  for (; j < deg; ++j){
    int s = __builtin_amdgcn_readfirstlane(srcs[base + j]);
    unsigned int u = *reinterpret_cast<const unsigned int*>(Xh + (size_t)s*HC + c0);
    float w = __expf(lrelu(asrc[s*NH + hd] + adh));
    wsum += w;
    accx += w*__uint_as_float(u << 16);
    accy += w*__uint_as_float(u & 0xffff0000u);
  }
  float inv = 1.f / wsum;
  accx = accx*inv + bias[c0];
  accy = accy*inv + bias[c0+1];
  if (do_relu){ accx = fmaxf(accx, 0.f); accy = fmaxf(accy, 0.f); }
  *reinterpret_cast<float2*>(out + (size_t)node*HC + c0) = make_float2(accx, accy);
}

// ---------------- pooling: group boundaries (batch is sorted) ----------------
__global__ void k_bounds(const int* __restrict__ batch, int* __restrict__ start, int N, int G){
  for (int i = blockIdx.x*blockDim.x + threadIdx.x; i <= N; i += gridDim.x*blockDim.x){
    int b  = (i < N) ? batch[i]   : G;
    int bp = (i > 0) ? batch[i-1] : -1;
    for (int g = bp + 1; g <= b; ++g) if (g <= G) start[g] = i;
  }
}

__global__ void k_pool_partial(const float* __restrict__ h2, const int* __restrict__ start,
                               float* __restrict__ psum, float* __restrict__ pmax, int G){
  int g = blockIdx.x / PSLICES, s = blockIdx.x % PSLICES;
  int c = threadIdx.x;   // 128 threads
  int st = start[g], en = start[g+1];
  float sm = 0.f, mx = -FLT_MAX;
  for (int i = st + s; i < en; i += PSLICES){
    float v = h2[(size_t)i*HC + c];
    sm += v; mx = fmaxf(mx, v);
  }
  psum[(g*PSLICES+s)*HC + c] = sm;
  pmax[(g*PSLICES+s)*HC + c] = mx;
}

// ---------------- final: reduce partials, normalize, two MLP heads ----------------
__global__ void k_head(const float* __restrict__ psum, const float* __restrict__ pmax,
                       const int* __restrict__ start,
                       const float* __restrict__ cW1, const float* __restrict__ cb1,
                       const float* __restrict__ cWo, const float* __restrict__ cbo,
                       const float* __restrict__ dW1, const float* __restrict__ db1,
                       const float* __restrict__ dWo, const float* __restrict__ dbo,
                       float* __restrict__ out, int G){
  __shared__ float feat[256];
  __shared__ float hid[128];
  __shared__ float red[2];
  int g = blockIdx.x;
  int t = threadIdx.x;   // 128
  int cnt = start[g+1] - start[g];
  float sm = 0.f, mx = -FLT_MAX;
  for (int s = 0; s < PSLICES; ++s){
    sm += psum[(g*PSLICES+s)*HC + t];
    mx = fmaxf(mx, pmax[(g*PSLICES+s)*HC + t]);
  }
  float mean = sm / (float)((cnt > 1) ? cnt : 1);
  feat[t] = mean; feat[128 + t] = mx;
  float sq = mean*mean + mx*mx;
  for (int d = 32; d; d >>= 1) sq += __shfl_xor(sq, d);
  if ((t & 63) == 0) red[t >> 6] = sq;
  __syncthreads();
  float norm = sqrtf(red[0] + red[1]);
  float scale = 1.f / fmaxf(norm, 1e-12f);
  feat[t] *= scale; feat[128 + t] *= scale;
  __syncthreads();
  float hsum = cb1[t];
  for (int k = 0; k < 256; ++k) hsum += feat[k]*cW1[k*128 + t];
  hid[t] = fmaxf(hsum, 0.f);
  __syncthreads();
  if (t < 8){
    float o = cbo[t];
    for (int k = 0; k < 128; ++k) o += hid[k]*cWo[k*8 + t];
    out[g*8 + t] = o;
  }
  __syncthreads();
  float dsum = db1[t];
  for (int k = 0; k < 256; ++k) dsum += feat[k]*dW1[k*128 + t];
  hid[t] = fmaxf(dsum, 0.f);
  __syncthreads();
  if (t < 3){
    float o = dbo[t];
    for (int k = 0; k < 128; ++k) o += hid[k]*dWo[k*3 + t];
    out[G*8 + g*3 + t] = o;
  }
}

extern "C" void kernel_launch(void* const* d_in, const int* in_sizes, int n_in,
                              void* d_out, int out_size, void* d_ws, size_t ws_size,
                              hipStream_t stream) {
  const float* x     = (const float*)d_in[0];
  const int*   ei    = (const int*)  d_in[1];
  const int*   batch = (const int*)  d_in[2];
  const float* eW1 = (const float*)d_in[4];
  const float* eas1= (const float*)d_in[5];
  const float* ead1= (const float*)d_in[6];
  const float* eb1 = (const float*)d_in[7];
  const float* eW2 = (const float*)d_in[8];
  const float* eas2= (const float*)d_in[9];
  const float* ead2= (const float*)d_in[10];
  const float* eb2 = (const float*)d_in[11];
  const float* cW1 = (const float*)d_in[12];
  const float* cb1 = (const float*)d_in[13];
  const float* cWo = (const float*)d_in[14];
  const float* cbo = (const float*)d_in[15];
  const float* dW1 = (const float*)d_in[16];
  const float* db1 = (const float*)d_in[17];
  const float* dWo = (const float*)d_in[18];
  const float* dbo = (const float*)d_in[19];

  const int N = in_sizes[0] / 64;
  const int E = in_sizes[1] / 2;
  const int G = 64;

  char* ws = (char*)d_ws;
  size_t off = 0;
  auto alloc = [&](size_t bytes)->void* {
    void* p = ws + off; off += (bytes + 255) & ~(size_t)255; return p;
  };
  int*   rowptr = (int*)  alloc((size_t)(N+1)*4);
  int*   cnt    = (int*)  alloc((size_t)N*4);
  int*   srcs   = (int*)  alloc((size_t)(E+N)*4);
  float* asrc   = (float*)alloc((size_t)N*NH*4);
  float* adst   = (float*)alloc((size_t)N*NH*4);
  unsigned short* bufH = (unsigned short*)alloc((size_t)N*HC*2);  // bf16 gather matrix
  float* bufB   = (float*)alloc((size_t)N*HC*4);
  int*   startg = (int*)  alloc((size_t)(G+1)*4);
  float* psum   = (float*)alloc((size_t)G*PSLICES*HC*4);
  float* pmax   = (float*)alloc((size_t)G*PSLICES*HC*4);
  int*   bsum   = (int*)  alloc((size_t)256*4);
  int*   ebsum  = (int*)  alloc((size_t)256*4);
  (void)ws_size; (void)n_in; (void)out_size;

  int total = E + N;
  int egrid = (total + 255) / 256; if (egrid > 4096) egrid = 4096;

  hipMemsetAsync(cnt, 0, (size_t)N*4, stream);
  k_deg<<<egrid, 256, 0, stream>>>(ei, cnt, E, N);
  int nb = (N + SEG - 1) / SEG;              // 25 blocks at N=50000 (<=256 supported)
  k_part <<<nb, 256, 0, stream>>>(cnt, bsum, N);
  k_scanb<<<1,  256, 0, stream>>>(bsum, ebsum, rowptr + N, nb);
  k_final<<<nb, 256, 0, stream>>>(cnt, ebsum, rowptr, N);
  hipMemsetAsync(cnt, 0, (size_t)N*4, stream);
  k_scatter<<<egrid, 256, 0, stream>>>(ei, rowptr, cnt, srcs, E, N);

  dim3 ggrid((N + 63) / 64, 2);
  // layer 1: h1 = relu(GAT(x) + b1)
  k_gemm_att<64><<<ggrid, 256, 0, stream>>>(x, eW1, eas1, ead1, bufH, asrc, adst, N);
  k_agg<<<(N+3)/4, 256, 0, stream>>>(bufH, asrc, adst, rowptr, srcs, eb1, bufB, N, 1);
  // layer 2: h2 = GAT(h1) + b2
  k_gemm_att<128><<<ggrid, 256, 0, stream>>>(bufB, eW2, eas2, ead2, bufH, asrc, adst, N);
  k_agg<<<(N+3)/4, 256, 0, stream>>>(bufH, asrc, adst, rowptr, srcs, eb2, bufB, N, 0);

  // pooling + heads
  k_bounds<<<64, 256, 0, stream>>>(batch, startg, N, G);
  k_pool_partial<<<G*PSLICES, 128, 0, stream>>>(bufB, startg, psum, pmax, G);
  k_head<<<G, 128, 0, stream>>>(psum, pmax, startg, cW1, cb1, cWo, cbo,
                                dW1, db1, dWo, dbo, (float*)d_out, G);
}

// Round 11
// 220.772 us; speedup vs baseline: 1.8966x; 1.2687x over previous
//
#include <hip/hip_runtime.h>
#include <float.h>

#define HC 128    // H*C
#define NH 4      // heads
#define PSLICES 8
#define BSHIFT 9  // 512 nodes per bucket
#define NBK 128   // allocated buckets (used: ceil(N/512)=98)
#define NBH 512   // histogram/bucket blocks

__device__ __forceinline__ float lrelu(float v){ return v > 0.f ? v : 0.2f*v; }

__device__ __forceinline__ unsigned short f2bf(float f){   // round-to-nearest-even
  unsigned int u = __float_as_uint(f);
  unsigned int r = (u + 0x7fffu + ((u >> 16) & 1u)) >> 16;
  return (unsigned short)r;
}

// ================= bucketed CSR build (counting sort by dst, L2-local scatters) ============
// Pass A: per-block LDS histogram over dst buckets.
__global__ void k_hist(const int* __restrict__ ei, int* __restrict__ gmat,
                       int E, int T, int chunk){
  __shared__ int h[NBK];
  int b = blockIdx.x, t = threadIdx.x;
  if (t < NBK) h[t] = 0;
  __syncthreads();
  int lo = b*chunk, hi = lo + chunk; if (hi > T) hi = T;
  for (int i = lo + t; i < hi; i += 256){
    int d = (i < E) ? ei[E + i] : (i - E);
    atomicAdd(&h[d >> BSHIFT], 1);
  }
  __syncthreads();
  if (t < NBK) gmat[(size_t)b*NBK + t] = h[t];
}

// Pass B1: per-bucket column scan over the 512 block counts (one block per bucket).
__global__ void k_colscan(int* __restrict__ gmat, int* __restrict__ coltot){
  __shared__ int part[256];
  int k = blockIdx.x, t = threadIdx.x;
  int v0 = gmat[(size_t)(2*t)*NBK + k];
  int v1 = gmat[(size_t)(2*t+1)*NBK + k];
  int s = v0 + v1;
  part[t] = s;
  __syncthreads();
  for (int off = 1; off < 256; off <<= 1){
    int v = (t >= off) ? part[t-off] : 0;
    __syncthreads();
    part[t] += v;
    __syncthreads();
  }
  int pre = part[t] - s;                       // exclusive prefix for this thread's pair
  gmat[(size_t)(2*t)*NBK + k]   = pre;
  gmat[(size_t)(2*t+1)*NBK + k] = pre + v0;
  if (t == 255) coltot[k] = part[255];
}

// Pass B2: scan bucket totals -> bucket start offsets; also rowptr[N] = total.
__global__ void k_bstart(const int* __restrict__ coltot, int* __restrict__ bstart,
                         int* __restrict__ rowptrN){
  __shared__ int part[NBK];
  int t = threadIdx.x;                         // 128
  int own = coltot[t];
  part[t] = own;
  __syncthreads();
  for (int off = 1; off < NBK; off <<= 1){
    int v = (t >= off) ? part[t-off] : 0;
    __syncthreads();
    part[t] += v;
    __syncthreads();
  }
  bstart[t] = part[t] - own;
  if (t == NBK-1){ bstart[NBK] = part[NBK-1]; *rowptrN = part[NBK-1]; }
}

// Pass C: scatter (dst,src) pairs into bucket-partitioned regions (contiguous runs/block).
__global__ void k_bucket(const int* __restrict__ ei, const int* __restrict__ gmat,
                         const int* __restrict__ bstart, int2* __restrict__ pairs,
                         int E, int T, int chunk){
  __shared__ int cnt[NBK];
  int b = blockIdx.x, t = threadIdx.x;
  if (t < NBK) cnt[t] = 0;
  __syncthreads();
  int lo = b*chunk, hi = lo + chunk; if (hi > T) hi = T;
  for (int i = lo + t; i < hi; i += 256){
    int s, d;
    if (i < E){ s = ei[i]; d = ei[E + i]; } else { s = d = i - E; }
    int k = d >> BSHIFT;
    int r = atomicAdd(&cnt[k], 1);
    int pos = bstart[k] + gmat[(size_t)b*NBK + k] + r;
    pairs[pos] = make_int2(d, s);
  }
}

// Pass D: per-bucket CSR finalize: LDS degree count + scan -> rowptr, then local scatter.
__global__ void k_csr(const int2* __restrict__ pairs, const int* __restrict__ bstart,
                      int* __restrict__ rowptr, int* __restrict__ srcs, int N){
  __shared__ int deg[512];
  __shared__ int off[512];
  __shared__ int part[256];
  int k = blockIdx.x, t = threadIdx.x;
  int nlo = k << BSHIFT;
  int nhi = nlo + 512; if (nhi > N) nhi = N;
  int nn = nhi - nlo;
  int elo = bstart[k], ehi = bstart[k+1];
  deg[t] = 0; deg[t + 256] = 0;
  __syncthreads();
  for (int i = elo + t; i < ehi; i += 256) atomicAdd(&deg[pairs[i].x - nlo], 1);
  __syncthreads();
  int v0 = deg[2*t], v1 = deg[2*t+1];
  int s = v0 + v1;
  part[t] = s;
  __syncthreads();
  for (int o = 1; o < 256; o <<= 1){
    int v = (t >= o) ? part[t-o] : 0;
    __syncthreads();
    part[t] += v;
    __syncthreads();
  }
  int pre = part[t] - s;
  off[2*t] = pre; off[2*t+1] = pre + v0;
  __syncthreads();
  for (int j = t; j < nn; j += 256) rowptr[nlo + j] = elo + off[j];
  deg[t] = 0; deg[t + 256] = 0;                // reuse as fill counters
  __syncthreads();
  for (int i = elo + t; i < ehi; i += 256){
    int2 p = pairs[i];
    int dl = p.x - nlo;
    int r = atomicAdd(&deg[dl], 1);
    srcs[elo + off[dl] + r] = p.y;
  }
}

// ---------------- LDS-tiled GEMM (X[N,K] @ W[K,128]) fused with attention reductions ----------
// Output H stored as bf16 (consumed only by the alpha-weighted gather in k_agg).
template<int K>
__global__ __launch_bounds__(256) void k_gemm_att(
    const float* __restrict__ X, const float* __restrict__ W,
    const float* __restrict__ as_, const float* __restrict__ ad_,
    unsigned short* __restrict__ Hb, float* __restrict__ asrc, float* __restrict__ adst,
    int n)
{
  __shared__ float Ws[64][64];     // [k][c] chunk
  __shared__ float Xs[64][68];     // [row][k] chunk, padded
  int tid = threadIdx.x;
  int tx = tid & 15;               // 16 col-groups of float4 -> 64 cols
  int ty = tid >> 4;               // 16 row-groups
  int row0 = blockIdx.x * 64;
  int cbase = blockIdx.y * 64;

  float4 acc[4];
  #pragma unroll
  for (int i = 0; i < 4; ++i) acc[i] = make_float4(0.f,0.f,0.f,0.f);

  for (int kc = 0; kc < K; kc += 64){
    #pragma unroll
    for (int p = 0; p < 4; ++p){
      int idx = tid + 256*p;
      int rr = idx >> 4, kk = (idx & 15) * 4;
      float4 w = *reinterpret_cast<const float4*>(W + (size_t)(kc + rr)*HC + cbase + kk);
      *reinterpret_cast<float4*>(&Ws[rr][kk]) = w;
    }
    #pragma unroll
    for (int p = 0; p < 4; ++p){
      int idx = tid + 256*p;
      int rr = idx >> 4, kk = (idx & 15) * 4;
      int g = row0 + rr;
      float4 v = make_float4(0.f,0.f,0.f,0.f);
      if (g < n) v = *reinterpret_cast<const float4*>(X + (size_t)g*K + kc + kk);
      *reinterpret_cast<float4*>(&Xs[rr][kk]) = v;
    }
    __syncthreads();
    #pragma unroll 4
    for (int k = 0; k < 64; ++k){
      float4 w = *reinterpret_cast<const float4*>(&Ws[k][tx*4]);
      #pragma unroll
      for (int i = 0; i < 4; ++i){
        float xv = Xs[ty + 16*i][k];
        acc[i].x += xv*w.x; acc[i].y += xv*w.y; acc[i].z += xv*w.z; acc[i].w += xv*w.w;
      }
    }
    __syncthreads();
  }

  int c0 = cbase + tx*4;
  int hd = c0 >> 5;
  float4 a4 = *reinterpret_cast<const float4*>(as_ + c0);
  float4 d4 = *reinterpret_cast<const float4*>(ad_ + c0);
  #pragma unroll
  for (int i = 0; i < 4; ++i){
    int row = row0 + ty + 16*i;
    float ps = acc[i].x*a4.x + acc[i].y*a4.y + acc[i].z*a4.z + acc[i].w*a4.w;
    float pd = acc[i].x*d4.x + acc[i].y*d4.y + acc[i].z*d4.z + acc[i].w*d4.w;
    ps += __shfl_down(ps, 4); pd += __shfl_down(pd, 4);
    ps += __shfl_down(ps, 2); pd += __shfl_down(pd, 2);
    ps += __shfl_down(ps, 1); pd += __shfl_down(pd, 1);
    if (row < n){
      uint2 pk;
      pk.x = (unsigned int)f2bf(acc[i].x) | ((unsigned int)f2bf(acc[i].y) << 16);
      pk.y = (unsigned int)f2bf(acc[i].z) | ((unsigned int)f2bf(acc[i].w) << 16);
      *reinterpret_cast<uint2*>(Hb + (size_t)row*HC + c0) = pk;
      if ((tx & 7) == 0){
        asrc[row*NH + hd] = ps;
        adst[row*NH + hd] = pd;
      }
    }
  }
}

// ---------------- fused edge softmax + aggregation: one wave per node, 4-edge unroll -------
// softmax without max-subtraction (scores are O(1) by construction: weights ~0.05):
// out = (sum_j exp(e_j) * h[src_j]) / (sum_j exp(e_j))  ==  reference softmax exactly.
// 4 independent row-gathers issued per iteration for memory-level parallelism.
__global__ void k_agg(const unsigned short* __restrict__ Xh, const float* __restrict__ asrc,
                      const float* __restrict__ adst, const int* __restrict__ rowptr,
                      const int* __restrict__ srcs, const float* __restrict__ bias,
                      float* __restrict__ out, int n, int do_relu)
{
  int lane = threadIdx.x & 63;
  int node = blockIdx.x*4 + (threadIdx.x >> 6);
  if (node >= n) return;
  int base = __builtin_amdgcn_readfirstlane(rowptr[node]);
  int deg  = __builtin_amdgcn_readfirstlane(rowptr[node+1]) - base;
  int hd = lane >> 4;                       // head for this lane's channels
  float adh = adst[node*NH + hd];
  int c0 = lane*2;                          // 2 channels per lane
  float accx = 0.f, accy = 0.f, wsum = 0.f;
  int j = 0;
  for (; j + 4 <= deg; j += 4){
    int s0 = __builtin_amdgcn_readfirstlane(srcs[base + j]);
    int s1 = __builtin_amdgcn_readfirstlane(srcs[base + j + 1]);
    int s2 = __builtin_amdgcn_readfirstlane(srcs[base + j + 2]);
    int s3 = __builtin_amdgcn_readfirstlane(srcs[base + j + 3]);
    unsigned int u0 = *reinterpret_cast<const unsigned int*>(Xh + (size_t)s0*HC + c0);
    unsigned int u1 = *reinterpret_cast<const unsigned int*>(Xh + (size_t)s1*HC + c0);
    unsigned int u2 = *reinterpret_cast<const unsigned int*>(Xh + (size_t)s2*HC + c0);
    unsigned int u3 = *reinterpret_cast<const unsigned int*>(Xh + (size_t)s3*HC + c0);
    float a0 = asrc[s0*NH + hd];
    float a1 = asrc[s1*NH + hd];
    float a2 = asrc[s2*NH + hd];
    float a3 = asrc[s3*NH + hd];
    float w0 = __expf(lrelu(a0 + adh));
    float w1 = __expf(lrelu(a1 + adh));
    float w2 = __expf(lrelu(a2 + adh));
    float w3 = __expf(lrelu(a3 + adh));
    wsum += (w0 + w1) + (w2 + w3);
    accx += w0*__uint_as_float(u0 << 16) + w1*__uint_as_float(u1 << 16)
          + w2*__uint_as_float(u2 << 16) + w3*__uint_as_float(u3 << 16);
    accy += w0*__uint_as_float(u0 & 0xffff0000u) + w1*__uint_as_float(u1 & 0xffff0000u)
          + w2*__uint_as_float(u2 & 0xffff0000u) + w3*__uint_as_float(u3 & 0xffff0000u);
  }
  for (; j < deg; ++j){
    int s = __builtin_amdgcn_readfirstlane(srcs[base + j]);
    unsigned int u = *reinterpret_cast<const unsigned int*>(Xh + (size_t)s*HC + c0);
    float w = __expf(lrelu(asrc[s*NH + hd] + adh));
    wsum += w;
    accx += w*__uint_as_float(u << 16);
    accy += w*__uint_as_float(u & 0xffff0000u);
  }
  float inv = 1.f / wsum;
  accx = accx*inv + bias[c0];
  accy = accy*inv + bias[c0+1];
  if (do_relu){ accx = fmaxf(accx, 0.f); accy = fmaxf(accy, 0.f); }
  *reinterpret_cast<float2*>(out + (size_t)node*HC + c0) = make_float2(accx, accy);
}

// ---------------- pooling: group boundaries (batch is sorted) ----------------
__global__ void k_bounds(const int* __restrict__ batch, int* __restrict__ start, int N, int G){
  for (int i = blockIdx.x*blockDim.x + threadIdx.x; i <= N; i += gridDim.x*blockDim.x){
    int b  = (i < N) ? batch[i]   : G;
    int bp = (i > 0) ? batch[i-1] : -1;
    for (int g = bp + 1; g <= b; ++g) if (g <= G) start[g] = i;
  }
}

__global__ void k_pool_partial(const float* __restrict__ h2, const int* __restrict__ start,
                               float* __restrict__ psum, float* __restrict__ pmax, int G){
  int g = blockIdx.x / PSLICES, s = blockIdx.x % PSLICES;
  int c = threadIdx.x;   // 128 threads
  int st = start[g], en = start[g+1];
  float sm = 0.f, mx = -FLT_MAX;
  for (int i = st + s; i < en; i += PSLICES){
    float v = h2[(size_t)i*HC + c];
    sm += v; mx = fmaxf(mx, v);
  }
  psum[(g*PSLICES+s)*HC + c] = sm;
  pmax[(g*PSLICES+s)*HC + c] = mx;
}

// ---------------- final: reduce partials, normalize, two MLP heads ----------------
__global__ void k_head(const float* __restrict__ psum, const float* __restrict__ pmax,
                       const int* __restrict__ start,
                       const float* __restrict__ cW1, const float* __restrict__ cb1,
                       const float* __restrict__ cWo, const float* __restrict__ cbo,
                       const float* __restrict__ dW1, const float* __restrict__ db1,
                       const float* __restrict__ dWo, const float* __restrict__ dbo,
                       float* __restrict__ out, int G){
  __shared__ float feat[256];
  __shared__ float hid[128];
  __shared__ float red[2];
  int g = blockIdx.x;
  int t = threadIdx.x;   // 128
  int cnt = start[g+1] - start[g];
  float sm = 0.f, mx = -FLT_MAX;
  for (int s = 0; s < PSLICES; ++s){
    sm += psum[(g*PSLICES+s)*HC + t];
    mx = fmaxf(mx, pmax[(g*PSLICES+s)*HC + t]);
  }
  float mean = sm / (float)((cnt > 1) ? cnt : 1);
  feat[t] = mean; feat[128 + t] = mx;
  float sq = mean*mean + mx*mx;
  for (int d = 32; d; d >>= 1) sq += __shfl_xor(sq, d);
  if ((t & 63) == 0) red[t >> 6] = sq;
  __syncthreads();
  float norm = sqrtf(red[0] + red[1]);
  float scale = 1.f / fmaxf(norm, 1e-12f);
  feat[t] *= scale; feat[128 + t] *= scale;
  __syncthreads();
  float hsum = cb1[t];
  for (int k = 0; k < 256; ++k) hsum += feat[k]*cW1[k*128 + t];
  hid[t] = fmaxf(hsum, 0.f);
  __syncthreads();
  if (t < 8){
    float o = cbo[t];
    for (int k = 0; k < 128; ++k) o += hid[k]*cWo[k*8 + t];
    out[g*8 + t] = o;
  }
  __syncthreads();
  float dsum = db1[t];
  for (int k = 0; k < 256; ++k) dsum += feat[k]*dW1[k*128 + t];
  hid[t] = fmaxf(dsum, 0.f);
  __syncthreads();
  if (t < 3){
    float o = dbo[t];
    for (int k = 0; k < 128; ++k) o += hid[k]*dWo[k*3 + t];
    out[G*8 + g*3 + t] = o;
  }
}

extern "C" void kernel_launch(void* const* d_in, const int* in_sizes, int n_in,
                              void* d_out, int out_size, void* d_ws, size_t ws_size,
                              hipStream_t stream) {
  const float* x     = (const float*)d_in[0];
  const int*   ei    = (const int*)  d_in[1];
  const int*   batch = (const int*)  d_in[2];
  const float* eW1 = (const float*)d_in[4];
  const float* eas1= (const float*)d_in[5];
  const float* ead1= (const float*)d_in[6];
  const float* eb1 = (const float*)d_in[7];
  const float* eW2 = (const float*)d_in[8];
  const float* eas2= (const float*)d_in[9];
  const float* ead2= (const float*)d_in[10];
  const float* eb2 = (const float*)d_in[11];
  const float* cW1 = (const float*)d_in[12];
  const float* cb1 = (const float*)d_in[13];
  const float* cWo = (const float*)d_in[14];
  const float* cbo = (const float*)d_in[15];
  const float* dW1 = (const float*)d_in[16];
  const float* db1 = (const float*)d_in[17];
  const float* dWo = (const float*)d_in[18];
  const float* dbo = (const float*)d_in[19];

  const int N = in_sizes[0] / 64;
  const int E = in_sizes[1] / 2;
  const int G = 64;
  const int T = E + N;

  char* ws = (char*)d_ws;
  size_t off = 0;
  auto alloc = [&](size_t bytes)->void* {
    void* p = ws + off; off += (bytes + 255) & ~(size_t)255; return p;
  };
  int*   rowptr = (int*)  alloc((size_t)(N+1)*4);
  int*   srcs   = (int*)  alloc((size_t)T*4);
  int2*  pairs  = (int2*) alloc((size_t)T*8);
  int*   gmat   = (int*)  alloc((size_t)NBH*NBK*4);
  int*   coltot = (int*)  alloc((size_t)NBK*4);
  int*   bstart = (int*)  alloc((size_t)(NBK+1)*4);
  float* asrc   = (float*)alloc((size_t)N*NH*4);
  float* adst   = (float*)alloc((size_t)N*NH*4);
  unsigned short* bufH = (unsigned short*)alloc((size_t)N*HC*2);  // bf16 gather matrix
  float* bufB   = (float*)alloc((size_t)N*HC*4);
  int*   startg = (int*)  alloc((size_t)(G+1)*4);
  float* psum   = (float*)alloc((size_t)G*PSLICES*HC*4);
  float* pmax   = (float*)alloc((size_t)G*PSLICES*HC*4);
  (void)ws_size; (void)n_in; (void)out_size;

  // ---- bucketed CSR build ----
  int chunk = (T + NBH - 1) / NBH;
  int nbuck = (N + (1 << BSHIFT) - 1) >> BSHIFT;      // 98
  k_hist   <<<NBH, 256, 0, stream>>>(ei, gmat, E, T, chunk);
  k_colscan<<<NBK, 256, 0, stream>>>(gmat, coltot);
  k_bstart <<<1,  NBK, 0, stream>>>(coltot, bstart, rowptr + N);
  k_bucket <<<NBH, 256, 0, stream>>>(ei, gmat, bstart, pairs, E, T, chunk);
  k_csr    <<<nbuck, 256, 0, stream>>>(pairs, bstart, rowptr, srcs, N);

  dim3 ggrid((N + 63) / 64, 2);
  // layer 1: h1 = relu(GAT(x) + b1)
  k_gemm_att<64><<<ggrid, 256, 0, stream>>>(x, eW1, eas1, ead1, bufH, asrc, adst, N);
  k_agg<<<(N+3)/4, 256, 0, stream>>>(bufH, asrc, adst, rowptr, srcs, eb1, bufB, N, 1);
  // layer 2: h2 = GAT(h1) + b2
  k_gemm_att<128><<<ggrid, 256, 0, stream>>>(bufB, eW2, eas2, ead2, bufH, asrc, adst, N);
  k_agg<<<(N+3)/4, 256, 0, stream>>>(bufH, asrc, adst, rowptr, srcs, eb2, bufB, N, 0);

  // pooling + heads
  k_bounds<<<64, 256, 0, stream>>>(batch, startg, N, G);
  k_pool_partial<<<G*PSLICES, 128, 0, stream>>>(bufB, startg, psum, pmax, G);
  k_head<<<G, 128, 0, stream>>>(psum, pmax, startg, cW1, cb1, cWo, cbo,
                                dW1, db1, dWo, dbo, (float*)d_out, G);
}

// Round 12
// 216.693 us; speedup vs baseline: 1.9323x; 1.0188x over previous
//
#include <hip/hip_runtime.h>
#include <float.h>

#define HC 128    // H*C
#define NH 4      // heads
#define PSLICES 8
#define BSHIFT 9  // 512 nodes per bucket
#define NBK 128   // allocated buckets (used: ceil(N/512)=98)
#define NBH 512   // histogram/bucket blocks

__device__ __forceinline__ float lrelu(float v){ return v > 0.f ? v : 0.2f*v; }

__device__ __forceinline__ unsigned short f2bf(float f){   // round-to-nearest-even
  unsigned int u = __float_as_uint(f);
  unsigned int r = (u + 0x7fffu + ((u >> 16) & 1u)) >> 16;
  return (unsigned short)r;
}

// ================= bucketed CSR build (counting sort by dst, L2-local scatters) ============
__global__ void k_hist(const int* __restrict__ ei, int* __restrict__ gmat,
                       int E, int T, int chunk){
  __shared__ int h[NBK];
  int b = blockIdx.x, t = threadIdx.x;
  if (t < NBK) h[t] = 0;
  __syncthreads();
  int lo = b*chunk, hi = lo + chunk; if (hi > T) hi = T;
  for (int i = lo + t; i < hi; i += 256){
    int d = (i < E) ? ei[E + i] : (i - E);
    atomicAdd(&h[d >> BSHIFT], 1);
  }
  __syncthreads();
  if (t < NBK) gmat[(size_t)b*NBK + t] = h[t];
}

__global__ void k_colscan(int* __restrict__ gmat, int* __restrict__ coltot){
  __shared__ int part[256];
  int k = blockIdx.x, t = threadIdx.x;
  int v0 = gmat[(size_t)(2*t)*NBK + k];
  int v1 = gmat[(size_t)(2*t+1)*NBK + k];
  int s = v0 + v1;
  part[t] = s;
  __syncthreads();
  for (int off = 1; off < 256; off <<= 1){
    int v = (t >= off) ? part[t-off] : 0;
    __syncthreads();
    part[t] += v;
    __syncthreads();
  }
  int pre = part[t] - s;                       // exclusive prefix for this thread's pair
  gmat[(size_t)(2*t)*NBK + k]   = pre;
  gmat[(size_t)(2*t+1)*NBK + k] = pre + v0;
  if (t == 255) coltot[k] = part[255];
}

__global__ void k_bstart(const int* __restrict__ coltot, int* __restrict__ bstart,
                         int* __restrict__ rowptrN){
  __shared__ int part[NBK];
  int t = threadIdx.x;                         // 128
  int own = coltot[t];
  part[t] = own;
  __syncthreads();
  for (int off = 1; off < NBK; off <<= 1){
    int v = (t >= off) ? part[t-off] : 0;
    __syncthreads();
    part[t] += v;
    __syncthreads();
  }
  bstart[t] = part[t] - own;
  if (t == NBK-1){ bstart[NBK] = part[NBK-1]; *rowptrN = part[NBK-1]; }
}

__global__ void k_bucket(const int* __restrict__ ei, const int* __restrict__ gmat,
                         const int* __restrict__ bstart, int2* __restrict__ pairs,
                         int E, int T, int chunk){
  __shared__ int cnt[NBK];
  int b = blockIdx.x, t = threadIdx.x;
  if (t < NBK) cnt[t] = 0;
  __syncthreads();
  int lo = b*chunk, hi = lo + chunk; if (hi > T) hi = T;
  for (int i = lo + t; i < hi; i += 256){
    int s, d;
    if (i < E){ s = ei[i]; d = ei[E + i]; } else { s = d = i - E; }
    int k = d >> BSHIFT;
    int r = atomicAdd(&cnt[k], 1);
    int pos = bstart[k] + gmat[(size_t)b*NBK + k] + r;
    pairs[pos] = make_int2(d, s);
  }
}

__global__ void k_csr(const int2* __restrict__ pairs, const int* __restrict__ bstart,
                      int* __restrict__ rowptr, int* __restrict__ srcs, int N){
  __shared__ int deg[512];
  __shared__ int off[512];
  __shared__ int part[256];
  int k = blockIdx.x, t = threadIdx.x;
  int nlo = k << BSHIFT;
  int nhi = nlo + 512; if (nhi > N) nhi = N;
  int nn = nhi - nlo;
  int elo = bstart[k], ehi = bstart[k+1];
  deg[t] = 0; deg[t + 256] = 0;
  __syncthreads();
  for (int i = elo + t; i < ehi; i += 256) atomicAdd(&deg[pairs[i].x - nlo], 1);
  __syncthreads();
  int v0 = deg[2*t], v1 = deg[2*t+1];
  int s = v0 + v1;
  part[t] = s;
  __syncthreads();
  for (int o = 1; o < 256; o <<= 1){
    int v = (t >= o) ? part[t-o] : 0;
    __syncthreads();
    part[t] += v;
    __syncthreads();
  }
  int pre = part[t] - s;
  off[2*t] = pre; off[2*t+1] = pre + v0;
  __syncthreads();
  for (int j = t; j < nn; j += 256) rowptr[nlo + j] = elo + off[j];
  deg[t] = 0; deg[t + 256] = 0;                // reuse as fill counters
  __syncthreads();
  for (int i = elo + t; i < ehi; i += 256){
    int2 p = pairs[i];
    int dl = p.x - nlo;
    int r = atomicAdd(&deg[dl], 1);
    srcs[elo + off[dl] + r] = p.y;
  }
}

// ---------------- LDS-tiled GEMM (X[N,K] @ W[K,128]) fused with attention reductions ----------
template<int K>
__global__ __launch_bounds__(256) void k_gemm_att(
    const float* __restrict__ X, const float* __restrict__ W,
    const float* __restrict__ as_, const float* __restrict__ ad_,
    unsigned short* __restrict__ Hb, float* __restrict__ asrc, float* __restrict__ adst,
    int n)
{
  __shared__ float Ws[64][64];     // [k][c] chunk
  __shared__ float Xs[64][68];     // [row][k] chunk, padded
  int tid = threadIdx.x;
  int tx = tid & 15;               // 16 col-groups of float4 -> 64 cols
  int ty = tid >> 4;               // 16 row-groups
  int row0 = blockIdx.x * 64;
  int cbase = blockIdx.y * 64;

  float4 acc[4];
  #pragma unroll
  for (int i = 0; i < 4; ++i) acc[i] = make_float4(0.f,0.f,0.f,0.f);

  for (int kc = 0; kc < K; kc += 64){
    #pragma unroll
    for (int p = 0; p < 4; ++p){
      int idx = tid + 256*p;
      int rr = idx >> 4, kk = (idx & 15) * 4;
      float4 w = *reinterpret_cast<const float4*>(W + (size_t)(kc + rr)*HC + cbase + kk);
      *reinterpret_cast<float4*>(&Ws[rr][kk]) = w;
    }
    #pragma unroll
    for (int p = 0; p < 4; ++p){
      int idx = tid + 256*p;
      int rr = idx >> 4, kk = (idx & 15) * 4;
      int g = row0 + rr;
      float4 v = make_float4(0.f,0.f,0.f,0.f);
      if (g < n) v = *reinterpret_cast<const float4*>(X + (size_t)g*K + kc + kk);
      *reinterpret_cast<float4*>(&Xs[rr][kk]) = v;
    }
    __syncthreads();
    #pragma unroll 4
    for (int k = 0; k < 64; ++k){
      float4 w = *reinterpret_cast<const float4*>(&Ws[k][tx*4]);
      #pragma unroll
      for (int i = 0; i < 4; ++i){
        float xv = Xs[ty + 16*i][k];
        acc[i].x += xv*w.x; acc[i].y += xv*w.y; acc[i].z += xv*w.z; acc[i].w += xv*w.w;
      }
    }
    __syncthreads();
  }

  int c0 = cbase + tx*4;
  int hd = c0 >> 5;
  float4 a4 = *reinterpret_cast<const float4*>(as_ + c0);
  float4 d4 = *reinterpret_cast<const float4*>(ad_ + c0);
  #pragma unroll
  for (int i = 0; i < 4; ++i){
    int row = row0 + ty + 16*i;
    float ps = acc[i].x*a4.x + acc[i].y*a4.y + acc[i].z*a4.z + acc[i].w*a4.w;
    float pd = acc[i].x*d4.x + acc[i].y*d4.y + acc[i].z*d4.z + acc[i].w*d4.w;
    ps += __shfl_down(ps, 4); pd += __shfl_down(pd, 4);
    ps += __shfl_down(ps, 2); pd += __shfl_down(pd, 2);
    ps += __shfl_down(ps, 1); pd += __shfl_down(pd, 1);
    if (row < n){
      uint2 pk;
      pk.x = (unsigned int)f2bf(acc[i].x) | ((unsigned int)f2bf(acc[i].y) << 16);
      pk.y = (unsigned int)f2bf(acc[i].z) | ((unsigned int)f2bf(acc[i].w) << 16);
      *reinterpret_cast<uint2*>(Hb + (size_t)row*HC + c0) = pk;
      if ((tx & 7) == 0){
        asrc[row*NH + hd] = ps;
        adst[row*NH + hd] = pd;
      }
    }
  }
}

// ---------------- fused edge softmax + aggregation: one wave per node, 8-edge unroll -------
// softmax without max-subtraction (scores are O(1) by construction: weights ~0.05):
// out = (sum_j exp(e_j) * h[src_j]) / (sum_j exp(e_j))  ==  reference softmax exactly.
// 8 independent row-gathers issued per iteration for memory-level parallelism.
__global__ void k_agg(const unsigned short* __restrict__ Xh, const float* __restrict__ asrc,
                      const float* __restrict__ adst, const int* __restrict__ rowptr,
                      const int* __restrict__ srcs, const float* __restrict__ bias,
                      float* __restrict__ out, int n, int do_relu)
{
  int lane = threadIdx.x & 63;
  int node = blockIdx.x*4 + (threadIdx.x >> 6);
  if (node >= n) return;
  int base = __builtin_amdgcn_readfirstlane(rowptr[node]);
  int deg  = __builtin_amdgcn_readfirstlane(rowptr[node+1]) - base;
  int hd = lane >> 4;                       // head for this lane's channels
  float adh = adst[node*NH + hd];
  int c0 = lane*2;                          // 2 channels per lane
  float accx = 0.f, accy = 0.f, wsum = 0.f;
  int j = 0;
  for (; j + 8 <= deg; j += 8){
    int s0 = __builtin_amdgcn_readfirstlane(srcs[base + j]);
    int s1 = __builtin_amdgcn_readfirstlane(srcs[base + j + 1]);
    int s2 = __builtin_amdgcn_readfirstlane(srcs[base + j + 2]);
    int s3 = __builtin_amdgcn_readfirstlane(srcs[base + j + 3]);
    int s4 = __builtin_amdgcn_readfirstlane(srcs[base + j + 4]);
    int s5 = __builtin_amdgcn_readfirstlane(srcs[base + j + 5]);
    int s6 = __builtin_amdgcn_readfirstlane(srcs[base + j + 6]);
    int s7 = __builtin_amdgcn_readfirstlane(srcs[base + j + 7]);
    unsigned int u0 = *reinterpret_cast<const unsigned int*>(Xh + (size_t)s0*HC + c0);
    unsigned int u1 = *reinterpret_cast<const unsigned int*>(Xh + (size_t)s1*HC + c0);
    unsigned int u2 = *reinterpret_cast<const unsigned int*>(Xh + (size_t)s2*HC + c0);
    unsigned int u3 = *reinterpret_cast<const unsigned int*>(Xh + (size_t)s3*HC + c0);
    unsigned int u4 = *reinterpret_cast<const unsigned int*>(Xh + (size_t)s4*HC + c0);
    unsigned int u5 = *reinterpret_cast<const unsigned int*>(Xh + (size_t)s5*HC + c0);
    unsigned int u6 = *reinterpret_cast<const unsigned int*>(Xh + (size_t)s6*HC + c0);
    unsigned int u7 = *reinterpret_cast<const unsigned int*>(Xh + (size_t)s7*HC + c0);
    float a0 = asrc[s0*NH + hd];
    float a1 = asrc[s1*NH + hd];
    float a2 = asrc[s2*NH + hd];
    float a3 = asrc[s3*NH + hd];
    float a4 = asrc[s4*NH + hd];
    float a5 = asrc[s5*NH + hd];
    float a6 = asrc[s6*NH + hd];
    float a7 = asrc[s7*NH + hd];
    float w0 = __expf(lrelu(a0 + adh));
    float w1 = __expf(lrelu(a1 + adh));
    float w2 = __expf(lrelu(a2 + adh));
    float w3 = __expf(lrelu(a3 + adh));
    float w4 = __expf(lrelu(a4 + adh));
    float w5 = __expf(lrelu(a5 + adh));
    float w6 = __expf(lrelu(a6 + adh));
    float w7 = __expf(lrelu(a7 + adh));
    wsum += ((w0 + w1) + (w2 + w3)) + ((w4 + w5) + (w6 + w7));
    accx += w0*__uint_as_float(u0 << 16) + w1*__uint_as_float(u1 << 16)
          + w2*__uint_as_float(u2 << 16) + w3*__uint_as_float(u3 << 16)
          + w4*__uint_as_float(u4 << 16) + w5*__uint_as_float(u5 << 16)
          + w6*__uint_as_float(u6 << 16) + w7*__uint_as_float(u7 << 16);
    accy += w0*__uint_as_float(u0 & 0xffff0000u) + w1*__uint_as_float(u1 & 0xffff0000u)
          + w2*__uint_as_float(u2 & 0xffff0000u) + w3*__uint_as_float(u3 & 0xffff0000u)
          + w4*__uint_as_float(u4 & 0xffff0000u) + w5*__uint_as_float(u5 & 0xffff0000u)
          + w6*__uint_as_float(u6 & 0xffff0000u) + w7*__uint_as_float(u7 & 0xffff0000u);
  }
  for (; j + 4 <= deg; j += 4){
    int s0 = __builtin_amdgcn_readfirstlane(srcs[base + j]);
    int s1 = __builtin_amdgcn_readfirstlane(srcs[base + j + 1]);
    int s2 = __builtin_amdgcn_readfirstlane(srcs[base + j + 2]);
    int s3 = __builtin_amdgcn_readfirstlane(srcs[base + j + 3]);
    unsigned int u0 = *reinterpret_cast<const unsigned int*>(Xh + (size_t)s0*HC + c0);
    unsigned int u1 = *reinterpret_cast<const unsigned int*>(Xh + (size_t)s1*HC + c0);
    unsigned int u2 = *reinterpret_cast<const unsigned int*>(Xh + (size_t)s2*HC + c0);
    unsigned int u3 = *reinterpret_cast<const unsigned int*>(Xh + (size_t)s3*HC + c0);
    float a0 = asrc[s0*NH + hd];
    float a1 = asrc[s1*NH + hd];
    float a2 = asrc[s2*NH + hd];
    float a3 = asrc[s3*NH + hd];
    float w0 = __expf(lrelu(a0 + adh));
    float w1 = __expf(lrelu(a1 + adh));
    float w2 = __expf(lrelu(a2 + adh));
    float w3 = __expf(lrelu(a3 + adh));
    wsum += (w0 + w1) + (w2 + w3);
    accx += w0*__uint_as_float(u0 << 16) + w1*__uint_as_float(u1 << 16)
          + w2*__uint_as_float(u2 << 16) + w3*__uint_as_float(u3 << 16);
    accy += w0*__uint_as_float(u0 & 0xffff0000u) + w1*__uint_as_float(u1 & 0xffff0000u)
          + w2*__uint_as_float(u2 & 0xffff0000u) + w3*__uint_as_float(u3 & 0xffff0000u);
  }
  for (; j < deg; ++j){
    int s = __builtin_amdgcn_readfirstlane(srcs[base + j]);
    unsigned int u = *reinterpret_cast<const unsigned int*>(Xh + (size_t)s*HC + c0);
    float w = __expf(lrelu(asrc[s*NH + hd] + adh));
    wsum += w;
    accx += w*__uint_as_float(u << 16);
    accy += w*__uint_as_float(u & 0xffff0000u);
  }
  float inv = 1.f / wsum;
  accx = accx*inv + bias[c0];
  accy = accy*inv + bias[c0+1];
  if (do_relu){ accx = fmaxf(accx, 0.f); accy = fmaxf(accy, 0.f); }
  *reinterpret_cast<float2*>(out + (size_t)node*HC + c0) = make_float2(accx, accy);
}

// ---------------- pooling: group boundaries (batch is sorted) ----------------
__global__ void k_bounds(const int* __restrict__ batch, int* __restrict__ start, int N, int G){
  for (int i = blockIdx.x*blockDim.x + threadIdx.x; i <= N; i += gridDim.x*blockDim.x){
    int b  = (i < N) ? batch[i]   : G;
    int bp = (i > 0) ? batch[i-1] : -1;
    for (int g = bp + 1; g <= b; ++g) if (g <= G) start[g] = i;
  }
}

__global__ void k_pool_partial(const float* __restrict__ h2, const int* __restrict__ start,
                               float* __restrict__ psum, float* __restrict__ pmax, int G){
  int g = blockIdx.x / PSLICES, s = blockIdx.x % PSLICES;
  int c = threadIdx.x;   // 128 threads
  int st = start[g], en = start[g+1];
  float sm = 0.f, mx = -FLT_MAX;
  for (int i = st + s; i < en; i += PSLICES){
    float v = h2[(size_t)i*HC + c];
    sm += v; mx = fmaxf(mx, v);
  }
  psum[(g*PSLICES+s)*HC + c] = sm;
  pmax[(g*PSLICES+s)*HC + c] = mx;
}

// ---------------- final: reduce partials, normalize, two MLP heads ----------------
__global__ void k_head(const float* __restrict__ psum, const float* __restrict__ pmax,
                       const int* __restrict__ start,
                       const float* __restrict__ cW1, const float* __restrict__ cb1,
                       const float* __restrict__ cWo, const float* __restrict__ cbo,
                       const float* __restrict__ dW1, const float* __restrict__ db1,
                       const float* __restrict__ dWo, const float* __restrict__ dbo,
                       float* __restrict__ out, int G){
  __shared__ float feat[256];
  __shared__ float hid[128];
  __shared__ float red[2];
  int g = blockIdx.x;
  int t = threadIdx.x;   // 128
  int cnt = start[g+1] - start[g];
  float sm = 0.f, mx = -FLT_MAX;
  for (int s = 0; s < PSLICES; ++s){
    sm += psum[(g*PSLICES+s)*HC + t];
    mx = fmaxf(mx, pmax[(g*PSLICES+s)*HC + t]);
  }
  float mean = sm / (float)((cnt > 1) ? cnt : 1);
  feat[t] = mean; feat[128 + t] = mx;
  float sq = mean*mean + mx*mx;
  for (int d = 32; d; d >>= 1) sq += __shfl_xor(sq, d);
  if ((t & 63) == 0) red[t >> 6] = sq;
  __syncthreads();
  float norm = sqrtf(red[0] + red[1]);
  float scale = 1.f / fmaxf(norm, 1e-12f);
  feat[t] *= scale; feat[128 + t] *= scale;
  __syncthreads();
  float hsum = cb1[t];
  for (int k = 0; k < 256; ++k) hsum += feat[k]*cW1[k*128 + t];
  hid[t] = fmaxf(hsum, 0.f);
  __syncthreads();
  if (t < 8){
    float o = cbo[t];
    for (int k = 0; k < 128; ++k) o += hid[k]*cWo[k*8 + t];
    out[g*8 + t] = o;
  }
  __syncthreads();
  float dsum = db1[t];
  for (int k = 0; k < 256; ++k) dsum += feat[k]*dW1[k*128 + t];
  hid[t] = fmaxf(dsum, 0.f);
  __syncthreads();
  if (t < 3){
    float o = dbo[t];
    for (int k = 0; k < 128; ++k) o += hid[k]*dWo[k*3 + t];
    out[G*8 + g*3 + t] = o;
  }
}

extern "C" void kernel_launch(void* const* d_in, const int* in_sizes, int n_in,
                              void* d_out, int out_size, void* d_ws, size_t ws_size,
                              hipStream_t stream) {
  const float* x     = (const float*)d_in[0];
  const int*   ei    = (const int*)  d_in[1];
  const int*   batch = (const int*)  d_in[2];
  const float* eW1 = (const float*)d_in[4];
  const float* eas1= (const float*)d_in[5];
  const float* ead1= (const float*)d_in[6];
  const float* eb1 = (const float*)d_in[7];
  const float* eW2 = (const float*)d_in[8];
  const float* eas2= (const float*)d_in[9];
  const float* ead2= (const float*)d_in[10];
  const float* eb2 = (const float*)d_in[11];
  const float* cW1 = (const float*)d_in[12];
  const float* cb1 = (const float*)d_in[13];
  const float* cWo = (const float*)d_in[14];
  const float* cbo = (const float*)d_in[15];
  const float* dW1 = (const float*)d_in[16];
  const float* db1 = (const float*)d_in[17];
  const float* dWo = (const float*)d_in[18];
  const float* dbo = (const float*)d_in[19];

  const int N = in_sizes[0] / 64;
  const int E = in_sizes[1] / 2;
  const int G = 64;
  const int T = E + N;

  char* ws = (char*)d_ws;
  size_t off = 0;
  auto alloc = [&](size_t bytes)->void* {
    void* p = ws + off; off += (bytes + 255) & ~(size_t)255; return p;
  };
  int*   rowptr = (int*)  alloc((size_t)(N+1)*4);
  int*   srcs   = (int*)  alloc((size_t)T*4);
  int2*  pairs  = (int2*) alloc((size_t)T*8);
  int*   gmat   = (int*)  alloc((size_t)NBH*NBK*4);
  int*   coltot = (int*)  alloc((size_t)NBK*4);
  int*   bstart = (int*)  alloc((size_t)(NBK+1)*4);
  float* asrc   = (float*)alloc((size_t)N*NH*4);
  float* adst   = (float*)alloc((size_t)N*NH*4);
  unsigned short* bufH = (unsigned short*)alloc((size_t)N*HC*2);  // bf16 gather matrix
  float* bufB   = (float*)alloc((size_t)N*HC*4);
  int*   startg = (int*)  alloc((size_t)(G+1)*4);
  float* psum   = (float*)alloc((size_t)G*PSLICES*HC*4);
  float* pmax   = (float*)alloc((size_t)G*PSLICES*HC*4);
  (void)ws_size; (void)n_in; (void)out_size;

  // ---- bucketed CSR build ----
  int chunk = (T + NBH - 1) / NBH;
  int nbuck = (N + (1 << BSHIFT) - 1) >> BSHIFT;      // 98
  k_hist   <<<NBH, 256, 0, stream>>>(ei, gmat, E, T, chunk);
  k_colscan<<<NBK, 256, 0, stream>>>(gmat, coltot);
  k_bstart <<<1,  NBK, 0, stream>>>(coltot, bstart, rowptr + N);
  k_bucket <<<NBH, 256, 0, stream>>>(ei, gmat, bstart, pairs, E, T, chunk);
  k_csr    <<<nbuck, 256, 0, stream>>>(pairs, bstart, rowptr, srcs, N);

  dim3 ggrid((N + 63) / 64, 2);
  // layer 1: h1 = relu(GAT(x) + b1)
  k_gemm_att<64><<<ggrid, 256, 0, stream>>>(x, eW1, eas1, ead1, bufH, asrc, adst, N);
  k_agg<<<(N+3)/4, 256, 0, stream>>>(bufH, asrc, adst, rowptr, srcs, eb1, bufB, N, 1);
  // layer 2: h2 = GAT(h1) + b2
  k_gemm_att<128><<<ggrid, 256, 0, stream>>>(bufB, eW2, eas2, ead2, bufH, asrc, adst, N);
  k_agg<<<(N+3)/4, 256, 0, stream>>>(bufH, asrc, adst, rowptr, srcs, eb2, bufB, N, 0);

  // pooling + heads
  k_bounds<<<64, 256, 0, stream>>>(batch, startg, N, G);
  k_pool_partial<<<G*PSLICES, 128, 0, stream>>>(bufB, startg, psum, pmax, G);
  k_head<<<G, 128, 0, stream>>>(psum, pmax, startg, cW1, cb1, cWo, cbo,
                                dW1, db1, dWo, dbo, (float*)d_out, G);
}

// Round 14
// 213.571 us; speedup vs baseline: 1.9606x; 1.0146x over previous
//
#include <hip/hip_runtime.h>
#include <float.h>

#define HC 128    // H*C
#define NH 4      // heads
#define PSLICES 8
#define BSHIFT 9  // 512 nodes per bucket
#define NBK 128   // allocated buckets (used: ceil(N/512)=98)
#define NBH 512   // histogram/bucket blocks
#define LDSN 14336 // k_csr LDS staging capacity (bucket avg ~8.7k edges)

__device__ __forceinline__ float lrelu(float v){ return v > 0.f ? v : 0.2f*v; }

__device__ __forceinline__ unsigned short f2bf(float f){   // round-to-nearest-even
  unsigned int u = __float_as_uint(f);
  unsigned int r = (u + 0x7fffu + ((u >> 16) & 1u)) >> 16;
  return (unsigned short)r;
}

__device__ __forceinline__ int lbound(const int* __restrict__ a, int n, int v){
  int lo = 0, hi = n;
  while (lo < hi){ int m = (lo + hi) >> 1; if (a[m] < v) lo = m + 1; else hi = m; }
  return lo;
}

// ================= bucketed CSR build (counting sort by dst, L2-local scatters) ============
__global__ void k_hist(const int* __restrict__ ei, int* __restrict__ gmat,
                       int E, int T, int chunk){
  __shared__ int h[NBK];
  int b = blockIdx.x, t = threadIdx.x;
  if (t < NBK) h[t] = 0;
  __syncthreads();
  int lo = b*chunk, hi = lo + chunk; if (hi > T) hi = T;
  for (int i = lo + t; i < hi; i += 256){
    int d = (i < E) ? ei[E + i] : (i - E);
    atomicAdd(&h[d >> BSHIFT], 1);
  }
  __syncthreads();
  if (t < NBK) gmat[(size_t)b*NBK + t] = h[t];
}

__global__ void k_colscan(int* __restrict__ gmat, int* __restrict__ coltot){
  __shared__ int part[256];
  int k = blockIdx.x, t = threadIdx.x;
  int v0 = gmat[(size_t)(2*t)*NBK + k];
  int v1 = gmat[(size_t)(2*t+1)*NBK + k];
  int s = v0 + v1;
  part[t] = s;
  __syncthreads();
  for (int off = 1; off < 256; off <<= 1){
    int v = (t >= off) ? part[t-off] : 0;
    __syncthreads();
    part[t] += v;
    __syncthreads();
  }
  int pre = part[t] - s;
  gmat[(size_t)(2*t)*NBK + k]   = pre;
  gmat[(size_t)(2*t+1)*NBK + k] = pre + v0;
  if (t == 255) coltot[k] = part[255];
}

__global__ void k_bstart(const int* __restrict__ coltot, int* __restrict__ bstart,
                         int* __restrict__ rowptrN){
  __shared__ int part[NBK];
  int t = threadIdx.x;                         // 128
  int own = coltot[t];
  part[t] = own;
  __syncthreads();
  for (int off = 1; off < NBK; off <<= 1){
    int v = (t >= off) ? part[t-off] : 0;
    __syncthreads();
    part[t] += v;
    __syncthreads();
  }
  bstart[t] = part[t] - own;
  if (t == NBK-1){ bstart[NBK] = part[NBK-1]; *rowptrN = part[NBK-1]; }
}

// pairs entry: (dst & 511) << 16 | src   (requires N <= 65535; here N = 50000)
__global__ void k_bucket(const int* __restrict__ ei, const int* __restrict__ gmat,
                         const int* __restrict__ bstart, int* __restrict__ pairs,
                         int E, int T, int chunk){
  __shared__ int cnt[NBK];
  int b = blockIdx.x, t = threadIdx.x;
  if (t < NBK) cnt[t] = 0;
  __syncthreads();
  int lo = b*chunk, hi = lo + chunk; if (hi > T) hi = T;
  for (int i = lo + t; i < hi; i += 256){
    int s, d;
    if (i < E){ s = ei[i]; d = ei[E + i]; } else { s = d = i - E; }
    int k = d >> BSHIFT;
    int r = atomicAdd(&cnt[k], 1);
    int pos = bstart[k] + gmat[(size_t)b*NBK + k] + r;
    pairs[pos] = ((d & ((1 << BSHIFT) - 1)) << 16) | s;
  }
}

__global__ void k_csr(const int* __restrict__ pairs, const int* __restrict__ bstart,
                      int* __restrict__ rowptr, int* __restrict__ srcs, int N){
  __shared__ int deg[512];
  __shared__ int off[512];
  __shared__ int part[256];
  __shared__ int sp[LDSN];
  int k = blockIdx.x, t = threadIdx.x;
  int nlo = k << BSHIFT;
  int nhi = nlo + 512; if (nhi > N) nhi = N;
  int nn = nhi - nlo;
  int elo = bstart[k], ehi = bstart[k+1];
  int ne = ehi - elo;
  bool uselds = (ne <= LDSN);
  deg[t] = 0; deg[t + 256] = 0;
  __syncthreads();
  if (uselds){
    for (int i = t; i < ne; i += 256){
      int p = pairs[elo + i];
      sp[i] = p;
      atomicAdd(&deg[p >> 16], 1);
    }
  } else {
    for (int i = t; i < ne; i += 256) atomicAdd(&deg[pairs[elo + i] >> 16], 1);
  }
  __syncthreads();
  int v0 = deg[2*t], v1 = deg[2*t+1];
  int s = v0 + v1;
  part[t] = s;
  __syncthreads();
  for (int o = 1; o < 256; o <<= 1){
    int v = (t >= o) ? part[t-o] : 0;
    __syncthreads();
    part[t] += v;
    __syncthreads();
  }
  int pre = part[t] - s;
  off[2*t] = pre; off[2*t+1] = pre + v0;
  __syncthreads();
  for (int j = t; j < nn; j += 256) rowptr[nlo + j] = elo + off[j];
  deg[t] = 0; deg[t + 256] = 0;                // reuse as fill counters
  __syncthreads();
  if (uselds){
    for (int i = t; i < ne; i += 256){
      int p = sp[i];
      int dl = p >> 16;
      int r = atomicAdd(&deg[dl], 1);
      srcs[elo + off[dl] + r] = p & 0xFFFF;
    }
  } else {
    for (int i = t; i < ne; i += 256){
      int p = pairs[elo + i];
      int dl = p >> 16;
      int r = atomicAdd(&deg[dl], 1);
      srcs[elo + off[dl] + r] = p & 0xFFFF;
    }
  }
}

// ---------------- LDS-tiled GEMM (X[N,K] @ W[K,128]) fused with attention reductions ----------
// INBF: X is bf16 (layer-2 path). Output H stored as bf16 gather matrix.
template<int K, bool INBF>
__global__ __launch_bounds__(256) void k_gemm_att(
    const void* __restrict__ Xv, const float* __restrict__ W,
    const float* __restrict__ as_, const float* __restrict__ ad_,
    unsigned short* __restrict__ Hb, float* __restrict__ asrc, float* __restrict__ adst,
    int n)
{
  __shared__ float Ws[64][64];     // [k][c] chunk
  __shared__ float Xs[64][68];     // [row][k] chunk, padded
  int tid = threadIdx.x;
  int tx = tid & 15;               // 16 col-groups of float4 -> 64 cols
  int ty = tid >> 4;               // 16 row-groups
  int row0 = blockIdx.x * 64;
  int cbase = blockIdx.y * 64;

  float4 acc[4];
  #pragma unroll
  for (int i = 0; i < 4; ++i) acc[i] = make_float4(0.f,0.f,0.f,0.f);

  for (int kc = 0; kc < K; kc += 64){
    #pragma unroll
    for (int p = 0; p < 4; ++p){
      int idx = tid + 256*p;
      int rr = idx >> 4, kk = (idx & 15) * 4;
      float4 w = *reinterpret_cast<const float4*>(W + (size_t)(kc + rr)*HC + cbase + kk);
      *reinterpret_cast<float4*>(&Ws[rr][kk]) = w;
    }
    if constexpr (INBF){
      const unsigned short* Xh16 = (const unsigned short*)Xv;
      #pragma unroll
      for (int p = 0; p < 2; ++p){
        int idx = tid + 256*p;               // 0..511
        int rr = idx >> 3, kk = (idx & 7) * 8;
        int g = row0 + rr;
        float4 lo = make_float4(0.f,0.f,0.f,0.f), hi = lo;
        if (g < n){
          uint4 v = *reinterpret_cast<const uint4*>(Xh16 + (size_t)g*K + kc + kk);
          lo.x = __uint_as_float(v.x << 16); lo.y = __uint_as_float(v.x & 0xffff0000u);
          lo.z = __uint_as_float(v.y << 16); lo.w = __uint_as_float(v.y & 0xffff0000u);
          hi.x = __uint_as_float(v.z << 16); hi.y = __uint_as_float(v.z & 0xffff0000u);
          hi.z = __uint_as_float(v.w << 16); hi.w = __uint_as_float(v.w & 0xffff0000u);
        }
        *reinterpret_cast<float4*>(&Xs[rr][kk])     = lo;
        *reinterpret_cast<float4*>(&Xs[rr][kk + 4]) = hi;
      }
    } else {
      const float* Xf = (const float*)Xv;
      #pragma unroll
      for (int p = 0; p < 4; ++p){
        int idx = tid + 256*p;
        int rr = idx >> 4, kk = (idx & 15) * 4;
        int g = row0 + rr;
        float4 v = make_float4(0.f,0.f,0.f,0.f);
        if (g < n) v = *reinterpret_cast<const float4*>(Xf + (size_t)g*K + kc + kk);
        *reinterpret_cast<float4*>(&Xs[rr][kk]) = v;
      }
    }
    __syncthreads();
    #pragma unroll 4
    for (int k = 0; k < 64; ++k){
      float4 w = *reinterpret_cast<const float4*>(&Ws[k][tx*4]);
      #pragma unroll
      for (int i = 0; i < 4; ++i){
        float xv = Xs[ty + 16*i][k];
        acc[i].x += xv*w.x; acc[i].y += xv*w.y; acc[i].z += xv*w.z; acc[i].w += xv*w.w;
      }
    }
    __syncthreads();
  }

  int c0 = cbase + tx*4;
  int hd = c0 >> 5;
  float4 a4 = *reinterpret_cast<const float4*>(as_ + c0);
  float4 d4 = *reinterpret_cast<const float4*>(ad_ + c0);
  #pragma unroll
  for (int i = 0; i < 4; ++i){
    int row = row0 + ty + 16*i;
    float ps = acc[i].x*a4.x + acc[i].y*a4.y + acc[i].z*a4.z + acc[i].w*a4.w;
    float pd = acc[i].x*d4.x + acc[i].y*d4.y + acc[i].z*d4.z + acc[i].w*d4.w;
    ps += __shfl_down(ps, 4); pd += __shfl_down(pd, 4);
    ps += __shfl_down(ps, 2); pd += __shfl_down(pd, 2);
    ps += __shfl_down(ps, 1); pd += __shfl_down(pd, 1);
    if (row < n){
      uint2 pk;
      pk.x = (unsigned int)f2bf(acc[i].x) | ((unsigned int)f2bf(acc[i].y) << 16);
      pk.y = (unsigned int)f2bf(acc[i].z) | ((unsigned int)f2bf(acc[i].w) << 16);
      *reinterpret_cast<uint2*>(Hb + (size_t)row*HC + c0) = pk;
      if ((tx & 7) == 0){
        asrc[row*NH + hd] = ps;
        adst[row*NH + hd] = pd;
      }
    }
  }
}

// ---------------- fused edge softmax + aggregation: one wave per node, 8-edge unroll -------
// OBF: pack output to bf16 (layer-1 activations feed only the layer-2 GEMM).
template<bool OBF>
__global__ void k_agg(const unsigned short* __restrict__ Xh, const float* __restrict__ asrc,
                      const float* __restrict__ adst, const int* __restrict__ rowptr,
                      const int* __restrict__ srcs, const float* __restrict__ bias,
                      void* __restrict__ outv, int n, int do_relu)
{
  int lane = threadIdx.x & 63;
  int node = blockIdx.x*4 + (threadIdx.x >> 6);
  if (node >= n) return;
  int base = __builtin_amdgcn_readfirstlane(rowptr[node]);
  int deg  = __builtin_amdgcn_readfirstlane(rowptr[node+1]) - base;
  int hd = lane >> 4;                       // head for this lane's channels
  float adh = adst[node*NH + hd];
  int c0 = lane*2;                          // 2 channels per lane
  float accx = 0.f, accy = 0.f, wsum = 0.f;
  int j = 0;
  for (; j + 8 <= deg; j += 8){
    int s0 = __builtin_amdgcn_readfirstlane(srcs[base + j]);
    int s1 = __builtin_amdgcn_readfirstlane(srcs[base + j + 1]);
    int s2 = __builtin_amdgcn_readfirstlane(srcs[base + j + 2]);
    int s3 = __builtin_amdgcn_readfirstlane(srcs[base + j + 3]);
    int s4 = __builtin_amdgcn_readfirstlane(srcs[base + j + 4]);
    int s5 = __builtin_amdgcn_readfirstlane(srcs[base + j + 5]);
    int s6 = __builtin_amdgcn_readfirstlane(srcs[base + j + 6]);
    int s7 = __builtin_amdgcn_readfirstlane(srcs[base + j + 7]);
    unsigned int u0 = *reinterpret_cast<const unsigned int*>(Xh + (size_t)s0*HC + c0);
    unsigned int u1 = *reinterpret_cast<const unsigned int*>(Xh + (size_t)s1*HC + c0);
    unsigned int u2 = *reinterpret_cast<const unsigned int*>(Xh + (size_t)s2*HC + c0);
    unsigned int u3 = *reinterpret_cast<const unsigned int*>(Xh + (size_t)s3*HC + c0);
    unsigned int u4 = *reinterpret_cast<const unsigned int*>(Xh + (size_t)s4*HC + c0);
    unsigned int u5 = *reinterpret_cast<const unsigned int*>(Xh + (size_t)s5*HC + c0);
    unsigned int u6 = *reinterpret_cast<const unsigned int*>(Xh + (size_t)s6*HC + c0);
    unsigned int u7 = *reinterpret_cast<const unsigned int*>(Xh + (size_t)s7*HC + c0);
    float a0 = asrc[s0*NH + hd];
    float a1 = asrc[s1*NH + hd];
    float a2 = asrc[s2*NH + hd];
    float a3 = asrc[s3*NH + hd];
    float a4 = asrc[s4*NH + hd];
    float a5 = asrc[s5*NH + hd];
    float a6 = asrc[s6*NH + hd];
    float a7 = asrc[s7*NH + hd];
    float w0 = __expf(lrelu(a0 + adh));
    float w1 = __expf(lrelu(a1 + adh));
    float w2 = __expf(lrelu(a2 + adh));
    float w3 = __expf(lrelu(a3 + adh));
    float w4 = __expf(lrelu(a4 + adh));
    float w5 = __expf(lrelu(a5 + adh));
    float w6 = __expf(lrelu(a6 + adh));
    float w7 = __expf(lrelu(a7 + adh));
    wsum += ((w0 + w1) + (w2 + w3)) + ((w4 + w5) + (w6 + w7));
    accx += w0*__uint_as_float(u0 << 16) + w1*__uint_as_float(u1 << 16)
          + w2*__uint_as_float(u2 << 16) + w3*__uint_as_float(u3 << 16)
          + w4*__uint_as_float(u4 << 16) + w5*__uint_as_float(u5 << 16)
          + w6*__uint_as_float(u6 << 16) + w7*__uint_as_float(u7 << 16);
    accy += w0*__uint_as_float(u0 & 0xffff0000u) + w1*__uint_as_float(u1 & 0xffff0000u)
          + w2*__uint_as_float(u2 & 0xffff0000u) + w3*__uint_as_float(u3 & 0xffff0000u)
          + w4*__uint_as_float(u4 & 0xffff0000u) + w5*__uint_as_float(u5 & 0xffff0000u)
          + w6*__uint_as_float(u6 & 0xffff0000u) + w7*__uint_as_float(u7 & 0xffff0000u);
  }
  for (; j + 4 <= deg; j += 4){
    int s0 = __builtin_amdgcn_readfirstlane(srcs[base + j]);
    int s1 = __builtin_amdgcn_readfirstlane(srcs[base + j + 1]);
    int s2 = __builtin_amdgcn_readfirstlane(srcs[base + j + 2]);
    int s3 = __builtin_amdgcn_readfirstlane(srcs[base + j + 3]);
    unsigned int u0 = *reinterpret_cast<const unsigned int*>(Xh + (size_t)s0*HC + c0);
    unsigned int u1 = *reinterpret_cast<const unsigned int*>(Xh + (size_t)s1*HC + c0);
    unsigned int u2 = *reinterpret_cast<const unsigned int*>(Xh + (size_t)s2*HC + c0);
    unsigned int u3 = *reinterpret_cast<const unsigned int*>(Xh + (size_t)s3*HC + c0);
    float a0 = asrc[s0*NH + hd];
    float a1 = asrc[s1*NH + hd];
    float a2 = asrc[s2*NH + hd];
    float a3 = asrc[s3*NH + hd];
    float w0 = __expf(lrelu(a0 + adh));
    float w1 = __expf(lrelu(a1 + adh));
    float w2 = __expf(lrelu(a2 + adh));
    float w3 = __expf(lrelu(a3 + adh));
    wsum += (w0 + w1) + (w2 + w3);
    accx += w0*__uint_as_float(u0 << 16) + w1*__uint_as_float(u1 << 16)
          + w2*__uint_as_float(u2 << 16) + w3*__uint_as_float(u3 << 16);
    accy += w0*__uint_as_float(u0 & 0xffff0000u) + w1*__uint_as_float(u1 & 0xffff0000u)
          + w2*__uint_as_float(u2 & 0xffff0000u) + w3*__uint_as_float(u3 & 0xffff0000u);
  }
  for (; j < deg; ++j){
    int s = __builtin_amdgcn_readfirstlane(srcs[base + j]);
    unsigned int u = *reinterpret_cast<const unsigned int*>(Xh + (size_t)s*HC + c0);
    float w = __expf(lrelu(asrc[s*NH + hd] + adh));
    wsum += w;
    accx += w*__uint_as_float(u << 16);
    accy += w*__uint_as_float(u & 0xffff0000u);
  }
  float inv = 1.f / wsum;
  accx = accx*inv + bias[c0];
  accy = accy*inv + bias[c0+1];
  if (do_relu){ accx = fmaxf(accx, 0.f); accy = fmaxf(accy, 0.f); }
  if constexpr (OBF){
    unsigned int pk = (unsigned int)f2bf(accx) | ((unsigned int)f2bf(accy) << 16);
    ((unsigned int*)outv)[(size_t)node*(HC/2) + lane] = pk;
  } else {
    *reinterpret_cast<float2*>((float*)outv + (size_t)node*HC + c0) = make_float2(accx, accy);
  }
}

// ---------------- pooling (group bounds via binary search on sorted batch) ----------------
__global__ void k_pool_partial(const float* __restrict__ h2, const int* __restrict__ batch,
                               float* __restrict__ psum, float* __restrict__ pmax, int N, int G){
  int g = blockIdx.x / PSLICES, s = blockIdx.x % PSLICES;
  int c = threadIdx.x;   // 128 threads
  int st = lbound(batch, N, g);
  int en = lbound(batch, N, g + 1);
  float sm = 0.f, mx = -FLT_MAX;
  for (int i = st + s; i < en; i += PSLICES){
    float v = h2[(size_t)i*HC + c];
    sm += v; mx = fmaxf(mx, v);
  }
  psum[(g*PSLICES+s)*HC + c] = sm;
  pmax[(g*PSLICES+s)*HC + c] = mx;
}

// ---------------- final: reduce partials, normalize, two MLP heads ----------------
__global__ void k_head(const float* __restrict__ psum, const float* __restrict__ pmax,
                       const int* __restrict__ batch,
                       const float* __restrict__ cW1, const float* __restrict__ cb1,
                       const float* __restrict__ cWo, const float* __restrict__ cbo,
                       const float* __restrict__ dW1, const float* __restrict__ db1,
                       const float* __restrict__ dWo, const float* __restrict__ dbo,
                       float* __restrict__ out, int N, int G){
  __shared__ float feat[256];
  __shared__ float hid[128];
  __shared__ float red[2];
  int g = blockIdx.x;
  int t = threadIdx.x;   // 128
  int cnt = lbound(batch, N, g + 1) - lbound(batch, N, g);
  float sm = 0.f, mx = -FLT_MAX;
  for (int s = 0; s < PSLICES; ++s){
    sm += psum[(g*PSLICES+s)*HC + t];
    mx = fmaxf(mx, pmax[(g*PSLICES+s)*HC + t]);
  }
  float mean = sm / (float)((cnt > 1) ? cnt : 1);
  feat[t] = mean; feat[128 + t] = mx;
  float sq = mean*mean + mx*mx;
  for (int d = 32; d; d >>= 1) sq += __shfl_xor(sq, d);
  if ((t & 63) == 0) red[t >> 6] = sq;
  __syncthreads();
  float norm = sqrtf(red[0] + red[1]);
  float scale = 1.f / fmaxf(norm, 1e-12f);
  feat[t] *= scale; feat[128 + t] *= scale;
  __syncthreads();
  float hsum = cb1[t];
  for (int k = 0; k < 256; ++k) hsum += feat[k]*cW1[k*128 + t];
  hid[t] = fmaxf(hsum, 0.f);
  __syncthreads();
  if (t < 8){
    float o = cbo[t];
    for (int k = 0; k < 128; ++k) o += hid[k]*cWo[k*8 + t];
    out[g*8 + t] = o;
  }
  __syncthreads();
  float dsum = db1[t];
  for (int k = 0; k < 256; ++k) dsum += feat[k]*dW1[k*128 + t];
  hid[t] = fmaxf(dsum, 0.f);
  __syncthreads();
  if (t < 3){
    float o = dbo[t];
    for (int k = 0; k < 128; ++k) o += hid[k]*dWo[k*3 + t];
    out[G*8 + g*3 + t] = o;
  }
}

extern "C" void kernel_launch(void* const* d_in, const int* in_sizes, int n_in,
                              void* d_out, int out_size, void* d_ws, size_t ws_size,
                              hipStream_t stream) {
  const float* x     = (const float*)d_in[0];
  const int*   ei    = (const int*)  d_in[1];
  const int*   batch = (const int*)  d_in[2];
  const float* eW1 = (const float*)d_in[4];
  const float* eas1= (const float*)d_in[5];
  const float* ead1= (const float*)d_in[6];
  const float* eb1 = (const float*)d_in[7];
  const float* eW2 = (const float*)d_in[8];
  const float* eas2= (const float*)d_in[9];
  const float* ead2= (const float*)d_in[10];
  const float* eb2 = (const float*)d_in[11];
  const float* cW1 = (const float*)d_in[12];
  const float* cb1 = (const float*)d_in[13];
  const float* cWo = (const float*)d_in[14];
  const float* cbo = (const float*)d_in[15];
  const float* dW1 = (const float*)d_in[16];
  const float* db1 = (const float*)d_in[17];
  const float* dWo = (const float*)d_in[18];
  const float* dbo = (const float*)d_in[19];

  const int N = in_sizes[0] / 64;
  const int E = in_sizes[1] / 2;
  const int G = 64;
  const int T = E + N;

  char* ws = (char*)d_ws;
  size_t off = 0;
  auto alloc = [&](size_t bytes)->void* {
    void* p = ws + off; off += (bytes + 255) & ~(size_t)255; return p;
  };
  int*   rowptr = (int*)  alloc((size_t)(N+1)*4);
  int*   srcs   = (int*)  alloc((size_t)T*4);
  int*   pairs  = (int*)  alloc((size_t)T*4);
  int*   gmat   = (int*)  alloc((size_t)NBH*NBK*4);
  int*   coltot = (int*)  alloc((size_t)NBK*4);
  int*   bstart = (int*)  alloc((size_t)(NBK+1)*4);
  float* asrc   = (float*)alloc((size_t)N*NH*4);
  float* adst   = (float*)alloc((size_t)N*NH*4);
  unsigned short* bufH  = (unsigned short*)alloc((size_t)N*HC*2);  // bf16 gather matrix
  unsigned short* bufX2 = (unsigned short*)alloc((size_t)N*HC*2);  // bf16 layer-1 activations
  float* bufB   = (float*)alloc((size_t)N*HC*4);                   // f32 h2 (pooling input)
  float* psum   = (float*)alloc((size_t)G*PSLICES*HC*4);
  float* pmax   = (float*)alloc((size_t)G*PSLICES*HC*4);
  (void)ws_size; (void)n_in; (void)out_size;

  // ---- bucketed CSR build ----
  int chunk = (T + NBH - 1) / NBH;
  int nbuck = (N + (1 << BSHIFT) - 1) >> BSHIFT;      // 98
  k_hist   <<<NBH, 256, 0, stream>>>(ei, gmat, E, T, chunk);
  k_colscan<<<NBK, 256, 0, stream>>>(gmat, coltot);
  k_bstart <<<1,  NBK, 0, stream>>>(coltot, bstart, rowptr + N);
  k_bucket <<<NBH, 256, 0, stream>>>(ei, gmat, bstart, pairs, E, T, chunk);
  k_csr    <<<nbuck, 256, 0, stream>>>(pairs, bstart, rowptr, srcs, N);

  dim3 ggrid((N + 63) / 64, 2);
  // layer 1: X2 = relu(GAT(x) + b1)  (stored bf16)
  k_gemm_att<64,false><<<ggrid, 256, 0, stream>>>(x, eW1, eas1, ead1, bufH, asrc, adst, N);
  k_agg<true><<<(N+3)/4, 256, 0, stream>>>(bufH, asrc, adst, rowptr, srcs, eb1, bufX2, N, 1);
  // layer 2: h2 = GAT(X2) + b2  (f32 for pooling)
  k_gemm_att<128,true><<<ggrid, 256, 0, stream>>>(bufX2, eW2, eas2, ead2, bufH, asrc, adst, N);
  k_agg<false><<<(N+3)/4, 256, 0, stream>>>(bufH, asrc, adst, rowptr, srcs, eb2, bufB, N, 0);

  // pooling + heads (group bounds via binary search on sorted batch)
  k_pool_partial<<<G*PSLICES, 128, 0, stream>>>(bufB, batch, psum, pmax, N, G);
  k_head<<<G, 128, 0, stream>>>(psum, pmax, batch, cW1, cb1, cWo, cbo,
                                dW1, db1, dWo, dbo, (float*)d_out, N, G);
}

// Round 16
// 213.472 us; speedup vs baseline: 1.9615x; 1.0005x over previous
//
#include <hip/hip_runtime.h>
#include <float.h>

#define HC 128    // H*C
#define NH 4      // heads
#define PSLICES 8
#define BSHIFT 9  // 512 nodes per bucket
#define NBK 128   // allocated buckets (used: ceil(N/512)=98)
#define NBH 512   // histogram/bucket blocks
#define LDSN 14336 // k_csr LDS staging capacity (bucket avg ~8.7k edges)

__device__ __forceinline__ float lrelu(float v){ return v > 0.f ? v : 0.2f*v; }

__device__ __forceinline__ unsigned short f2bf(float f){   // round-to-nearest-even
  unsigned int u = __float_as_uint(f);
  unsigned int r = (u + 0x7fffu + ((u >> 16) & 1u)) >> 16;
  return (unsigned short)r;
}

__device__ __forceinline__ int lbound(const int* __restrict__ a, int n, int v){
  int lo = 0, hi = n;
  while (lo < hi){ int m = (lo + hi) >> 1; if (a[m] < v) lo = m + 1; else hi = m; }
  return lo;
}

// ================= bucketed CSR build (counting sort by dst, L2-local scatters) ============
__global__ void k_hist(const int* __restrict__ ei, int* __restrict__ gmat,
                       int E, int T, int chunk){
  __shared__ int h[NBK];
  int b = blockIdx.x, t = threadIdx.x;
  if (t < NBK) h[t] = 0;
  __syncthreads();
  int lo = b*chunk, hi = lo + chunk; if (hi > T) hi = T;
  for (int i = lo + t; i < hi; i += 256){
    int d = (i < E) ? ei[E + i] : (i - E);
    atomicAdd(&h[d >> BSHIFT], 1);
  }
  __syncthreads();
  if (t < NBK) gmat[(size_t)b*NBK + t] = h[t];
}

__global__ void k_colscan(int* __restrict__ gmat, int* __restrict__ coltot){
  __shared__ int part[256];
  int k = blockIdx.x, t = threadIdx.x;
  int v0 = gmat[(size_t)(2*t)*NBK + k];
  int v1 = gmat[(size_t)(2*t+1)*NBK + k];
  int s = v0 + v1;
  part[t] = s;
  __syncthreads();
  for (int off = 1; off < 256; off <<= 1){
    int v = (t >= off) ? part[t-off] : 0;
    __syncthreads();
    part[t] += v;
    __syncthreads();
  }
  int pre = part[t] - s;
  gmat[(size_t)(2*t)*NBK + k]   = pre;
  gmat[(size_t)(2*t+1)*NBK + k] = pre + v0;
  if (t == 255) coltot[k] = part[255];
}

__global__ void k_bstart(const int* __restrict__ coltot, int* __restrict__ bstart,
                         int* __restrict__ rowptrN){
  __shared__ int part[NBK];
  int t = threadIdx.x;                         // 128
  int own = coltot[t];
  part[t] = own;
  __syncthreads();
  for (int off = 1; off < NBK; off <<= 1){
    int v = (t >= off) ? part[t-off] : 0;
    __syncthreads();
    part[t] += v;
    __syncthreads();
  }
  bstart[t] = part[t] - own;
  if (t == NBK-1){ bstart[NBK] = part[NBK-1]; *rowptrN = part[NBK-1]; }
}

// pairs entry: (dst & 511) << 16 | src   (requires N <= 65535; here N = 50000)
__global__ void k_bucket(const int* __restrict__ ei, const int* __restrict__ gmat,
                         const int* __restrict__ bstart, int* __restrict__ pairs,
                         int E, int T, int chunk){
  __shared__ int cnt[NBK];
  int b = blockIdx.x, t = threadIdx.x;
  if (t < NBK) cnt[t] = 0;
  __syncthreads();
  int lo = b*chunk, hi = lo + chunk; if (hi > T) hi = T;
  for (int i = lo + t; i < hi; i += 256){
    int s, d;
    if (i < E){ s = ei[i]; d = ei[E + i]; } else { s = d = i - E; }
    int k = d >> BSHIFT;
    int r = atomicAdd(&cnt[k], 1);
    int pos = bstart[k] + gmat[(size_t)b*NBK + k] + r;
    pairs[pos] = ((d & ((1 << BSHIFT) - 1)) << 16) | s;
  }
}

__global__ void k_csr(const int* __restrict__ pairs, const int* __restrict__ bstart,
                      int* __restrict__ rowptr, int* __restrict__ srcs, int N){
  __shared__ int deg[512];
  __shared__ int off[512];
  __shared__ int part[256];
  __shared__ int sp[LDSN];
  int k = blockIdx.x, t = threadIdx.x;
  int nlo = k << BSHIFT;
  int nhi = nlo + 512; if (nhi > N) nhi = N;
  int nn = nhi - nlo;
  int elo = bstart[k], ehi = bstart[k+1];
  int ne = ehi - elo;
  bool uselds = (ne <= LDSN);
  deg[t] = 0; deg[t + 256] = 0;
  __syncthreads();
  if (uselds){
    for (int i = t; i < ne; i += 256){
      int p = pairs[elo + i];
      sp[i] = p;
      atomicAdd(&deg[p >> 16], 1);
    }
  } else {
    for (int i = t; i < ne; i += 256) atomicAdd(&deg[pairs[elo + i] >> 16], 1);
  }
  __syncthreads();
  int v0 = deg[2*t], v1 = deg[2*t+1];
  int s = v0 + v1;
  part[t] = s;
  __syncthreads();
  for (int o = 1; o < 256; o <<= 1){
    int v = (t >= o) ? part[t-o] : 0;
    __syncthreads();
    part[t] += v;
    __syncthreads();
  }
  int pre = part[t] - s;
  off[2*t] = pre; off[2*t+1] = pre + v0;
  __syncthreads();
  for (int j = t; j < nn; j += 256) rowptr[nlo + j] = elo + off[j];
  deg[t] = 0; deg[t + 256] = 0;                // reuse as fill counters
  __syncthreads();
  if (uselds){
    for (int i = t; i < ne; i += 256){
      int p = sp[i];
      int dl = p >> 16;
      int r = atomicAdd(&deg[dl], 1);
      srcs[elo + off[dl] + r] = p & 0xFFFF;
    }
  } else {
    for (int i = t; i < ne; i += 256){
      int p = pairs[elo + i];
      int dl = p >> 16;
      int r = atomicAdd(&deg[dl], 1);
      srcs[elo + off[dl] + r] = p & 0xFFFF;
    }
  }
}

// ---------------- LDS-tiled GEMM (X[N,K] @ W[K,128]) fused with attention reductions ----------
// INBF: X is bf16 (layer-2 path). Output H stored as bf16 gather matrix.
template<int K, bool INBF>
__global__ __launch_bounds__(256) void k_gemm_att(
    const void* __restrict__ Xv, const float* __restrict__ W,
    const float* __restrict__ as_, const float* __restrict__ ad_,
    unsigned short* __restrict__ Hb, float* __restrict__ asrc, float* __restrict__ adst,
    int n)
{
  __shared__ float Ws[64][64];     // [k][c] chunk
  __shared__ float Xs[64][68];     // [row][k] chunk, padded
  int tid = threadIdx.x;
  int tx = tid & 15;               // 16 col-groups of float4 -> 64 cols
  int ty = tid >> 4;               // 16 row-groups
  int row0 = blockIdx.x * 64;
  int cbase = blockIdx.y * 64;

  float4 acc[4];
  #pragma unroll
  for (int i = 0; i < 4; ++i) acc[i] = make_float4(0.f,0.f,0.f,0.f);

  for (int kc = 0; kc < K; kc += 64){
    #pragma unroll
    for (int p = 0; p < 4; ++p){
      int idx = tid + 256*p;
      int rr = idx >> 4, kk = (idx & 15) * 4;
      float4 w = *reinterpret_cast<const float4*>(W + (size_t)(kc + rr)*HC + cbase + kk);
      *reinterpret_cast<float4*>(&Ws[rr][kk]) = w;
    }
    if constexpr (INBF){
      const unsigned short* Xh16 = (const unsigned short*)Xv;
      #pragma unroll
      for (int p = 0; p < 2; ++p){
        int idx = tid + 256*p;               // 0..511
        int rr = idx >> 3, kk = (idx & 7) * 8;
        int g = row0 + rr;
        float4 lo = make_float4(0.f,0.f,0.f,0.f), hi = lo;
        if (g < n){
          uint4 v = *reinterpret_cast<const uint4*>(Xh16 + (size_t)g*K + kc + kk);
          lo.x = __uint_as_float(v.x << 16); lo.y = __uint_as_float(v.x & 0xffff0000u);
          lo.z = __uint_as_float(v.y << 16); lo.w = __uint_as_float(v.y & 0xffff0000u);
          hi.x = __uint_as_float(v.z << 16); hi.y = __uint_as_float(v.z & 0xffff0000u);
          hi.z = __uint_as_float(v.w << 16); hi.w = __uint_as_float(v.w & 0xffff0000u);
        }
        *reinterpret_cast<float4*>(&Xs[rr][kk])     = lo;
        *reinterpret_cast<float4*>(&Xs[rr][kk + 4]) = hi;
      }
    } else {
      const float* Xf = (const float*)Xv;
      #pragma unroll
      for (int p = 0; p < 4; ++p){
        int idx = tid + 256*p;
        int rr = idx >> 4, kk = (idx & 15) * 4;
        int g = row0 + rr;
        float4 v = make_float4(0.f,0.f,0.f,0.f);
        if (g < n) v = *reinterpret_cast<const float4*>(Xf + (size_t)g*K + kc + kk);
        *reinterpret_cast<float4*>(&Xs[rr][kk]) = v;
      }
    }
    __syncthreads();
    #pragma unroll 4
    for (int k = 0; k < 64; ++k){
      float4 w = *reinterpret_cast<const float4*>(&Ws[k][tx*4]);
      #pragma unroll
      for (int i = 0; i < 4; ++i){
        float xv = Xs[ty + 16*i][k];
        acc[i].x += xv*w.x; acc[i].y += xv*w.y; acc[i].z += xv*w.z; acc[i].w += xv*w.w;
      }
    }
    __syncthreads();
  }

  int c0 = cbase + tx*4;
  int hd = c0 >> 5;
  float4 a4 = *reinterpret_cast<const float4*>(as_ + c0);
  float4 d4 = *reinterpret_cast<const float4*>(ad_ + c0);
  #pragma unroll
  for (int i = 0; i < 4; ++i){
    int row = row0 + ty + 16*i;
    float ps = acc[i].x*a4.x + acc[i].y*a4.y + acc[i].z*a4.z + acc[i].w*a4.w;
    float pd = acc[i].x*d4.x + acc[i].y*d4.y + acc[i].z*d4.z + acc[i].w*d4.w;
    ps += __shfl_down(ps, 4); pd += __shfl_down(pd, 4);
    ps += __shfl_down(ps, 2); pd += __shfl_down(pd, 2);
    ps += __shfl_down(ps, 1); pd += __shfl_down(pd, 1);
    if (row < n){
      uint2 pk;
      pk.x = (unsigned int)f2bf(acc[i].x) | ((unsigned int)f2bf(acc[i].y) << 16);
      pk.y = (unsigned int)f2bf(acc[i].z) | ((unsigned int)f2bf(acc[i].w) << 16);
      *reinterpret_cast<uint2*>(Hb + (size_t)row*HC + c0) = pk;
      if ((tx & 7) == 0){
        asrc[row*NH + hd] = ps;
        adst[row*NH + hd] = pd;
      }
    }
  }
}

// ---------------- fused edge softmax + aggregation: one wave per node, 8-edge unroll -------
// OBF: pack output to bf16 (layer-1 activations feed only the layer-2 GEMM).
template<bool OBF>
__global__ void k_agg(const unsigned short* __restrict__ Xh, const float* __restrict__ asrc,
                      const float* __restrict__ adst, const int* __restrict__ rowptr,
                      const int* __restrict__ srcs, const float* __restrict__ bias,
                      void* __restrict__ outv, int n, int do_relu)
{
  int lane = threadIdx.x & 63;
  int node = blockIdx.x*4 + (threadIdx.x >> 6);
  if (node >= n) return;
  int base = __builtin_amdgcn_readfirstlane(rowptr[node]);
  int deg  = __builtin_amdgcn_readfirstlane(rowptr[node+1]) - base;
  int hd = lane >> 4;                       // head for this lane's channels
  float adh = adst[node*NH + hd];
  int c0 = lane*2;                          // 2 channels per lane
  float accx = 0.f, accy = 0.f, wsum = 0.f;
  int j = 0;
  for (; j + 8 <= deg; j += 8){
    int s0 = __builtin_amdgcn_readfirstlane(srcs[base + j]);
    int s1 = __builtin_amdgcn_readfirstlane(srcs[base + j + 1]);
    int s2 = __builtin_amdgcn_readfirstlane(srcs[base + j + 2]);
    int s3 = __builtin_amdgcn_readfirstlane(srcs[base + j + 3]);
    int s4 = __builtin_amdgcn_readfirstlane(srcs[base + j + 4]);
    int s5 = __builtin_amdgcn_readfirstlane(srcs[base + j + 5]);
    int s6 = __builtin_amdgcn_readfirstlane(srcs[base + j + 6]);
    int s7 = __builtin_amdgcn_readfirstlane(srcs[base + j + 7]);
    unsigned int u0 = *reinterpret_cast<const unsigned int*>(Xh + (size_t)s0*HC + c0);
    unsigned int u1 = *reinterpret_cast<const unsigned int*>(Xh + (size_t)s1*HC + c0);
    unsigned int u2 = *reinterpret_cast<const unsigned int*>(Xh + (size_t)s2*HC + c0);
    unsigned int u3 = *reinterpret_cast<const unsigned int*>(Xh + (size_t)s3*HC + c0);
    unsigned int u4 = *reinterpret_cast<const unsigned int*>(Xh + (size_t)s4*HC + c0);
    unsigned int u5 = *reinterpret_cast<const unsigned int*>(Xh + (size_t)s5*HC + c0);
    unsigned int u6 = *reinterpret_cast<const unsigned int*>(Xh + (size_t)s6*HC + c0);
    unsigned int u7 = *reinterpret_cast<const unsigned int*>(Xh + (size_t)s7*HC + c0);
    float a0 = asrc[s0*NH + hd];
    float a1 = asrc[s1*NH + hd];
    float a2 = asrc[s2*NH + hd];
    float a3 = asrc[s3*NH + hd];
    float a4 = asrc[s4*NH + hd];
    float a5 = asrc[s5*NH + hd];
    float a6 = asrc[s6*NH + hd];
    float a7 = asrc[s7*NH + hd];
    float w0 = __expf(lrelu(a0 + adh));
    float w1 = __expf(lrelu(a1 + adh));
    float w2 = __expf(lrelu(a2 + adh));
    float w3 = __expf(lrelu(a3 + adh));
    float w4 = __expf(lrelu(a4 + adh));
    float w5 = __expf(lrelu(a5 + adh));
    float w6 = __expf(lrelu(a6 + adh));
    float w7 = __expf(lrelu(a7 + adh));
    wsum += ((w0 + w1) + (w2 + w3)) + ((w4 + w5) + (w6 + w7));
    accx += w0*__uint_as_float(u0 << 16) + w1*__uint_as_float(u1 << 16)
          + w2*__uint_as_float(u2 << 16) + w3*__uint_as_float(u3 << 16)
          + w4*__uint_as_float(u4 << 16) + w5*__uint_as_float(u5 << 16)
          + w6*__uint_as_float(u6 << 16) + w7*__uint_as_float(u7 << 16);
    accy += w0*__uint_as_float(u0 & 0xffff0000u) + w1*__uint_as_float(u1 & 0xffff0000u)
          + w2*__uint_as_float(u2 & 0xffff0000u) + w3*__uint_as_float(u3 & 0xffff0000u)
          + w4*__uint_as_float(u4 & 0xffff0000u) + w5*__uint_as_float(u5 & 0xffff0000u)
          + w6*__uint_as_float(u6 & 0xffff0000u) + w7*__uint_as_float(u7 & 0xffff0000u);
  }
  for (; j + 4 <= deg; j += 4){
    int s0 = __builtin_amdgcn_readfirstlane(srcs[base + j]);
    int s1 = __builtin_amdgcn_readfirstlane(srcs[base + j + 1]);
    int s2 = __builtin_amdgcn_readfirstlane(srcs[base + j + 2]);
    int s3 = __builtin_amdgcn_readfirstlane(srcs[base + j + 3]);
    unsigned int u0 = *reinterpret_cast<const unsigned int*>(Xh + (size_t)s0*HC + c0);
    unsigned int u1 = *reinterpret_cast<const unsigned int*>(Xh + (size_t)s1*HC + c0);
    unsigned int u2 = *reinterpret_cast<const unsigned int*>(Xh + (size_t)s2*HC + c0);
    unsigned int u3 = *reinterpret_cast<const unsigned int*>(Xh + (size_t)s3*HC + c0);
    float a0 = asrc[s0*NH + hd];
    float a1 = asrc[s1*NH + hd];
    float a2 = asrc[s2*NH + hd];
    float a3 = asrc[s3*NH + hd];
    float w0 = __expf(lrelu(a0 + adh));
    float w1 = __expf(lrelu(a1 + adh));
    float w2 = __expf(lrelu(a2 + adh));
    float w3 = __expf(lrelu(a3 + adh));
    wsum += (w0 + w1) + (w2 + w3);
    accx += w0*__uint_as_float(u0 << 16) + w1*__uint_as_float(u1 << 16)
          + w2*__uint_as_float(u2 << 16) + w3*__uint_as_float(u3 << 16);
    accy += w0*__uint_as_float(u0 & 0xffff0000u) + w1*__uint_as_float(u1 & 0xffff0000u)
          + w2*__uint_as_float(u2 & 0xffff0000u) + w3*__uint_as_float(u3 & 0xffff0000u);
  }
  for (; j < deg; ++j){
    int s = __builtin_amdgcn_readfirstlane(srcs[base + j]);
    unsigned int u = *reinterpret_cast<const unsigned int*>(Xh + (size_t)s*HC + c0);
    float w = __expf(lrelu(asrc[s*NH + hd] + adh));
    wsum += w;
    accx += w*__uint_as_float(u << 16);
    accy += w*__uint_as_float(u & 0xffff0000u);
  }
  float inv = 1.f / wsum;
  accx = accx*inv + bias[c0];
  accy = accy*inv + bias[c0+1];
  if (do_relu){ accx = fmaxf(accx, 0.f); accy = fmaxf(accy, 0.f); }
  if constexpr (OBF){
    unsigned int pk = (unsigned int)f2bf(accx) | ((unsigned int)f2bf(accy) << 16);
    ((unsigned int*)outv)[(size_t)node*(HC/2) + lane] = pk;
  } else {
    *reinterpret_cast<float2*>((float*)outv + (size_t)node*HC + c0) = make_float2(accx, accy);
  }
}

// ---------------- pooling (group bounds via binary search on sorted batch) ----------------
__global__ void k_pool_partial(const float* __restrict__ h2, const int* __restrict__ batch,
                               float* __restrict__ psum, float* __restrict__ pmax, int N, int G){
  int g = blockIdx.x / PSLICES, s = blockIdx.x % PSLICES;
  int c = threadIdx.x;   // 128 threads
  int st = lbound(batch, N, g);
  int en = lbound(batch, N, g + 1);
  float sm = 0.f, mx = -FLT_MAX;
  for (int i = st + s; i < en; i += PSLICES){
    float v = h2[(size_t)i*HC + c];
    sm += v; mx = fmaxf(mx, v);
  }
  psum[(g*PSLICES+s)*HC + c] = sm;
  pmax[(g*PSLICES+s)*HC + c] = mx;
}

// ---------------- final: reduce partials, normalize, two MLP heads ----------------
__global__ void k_head(const float* __restrict__ psum, const float* __restrict__ pmax,
                       const int* __restrict__ batch,
                       const float* __restrict__ cW1, const float* __restrict__ cb1,
                       const float* __restrict__ cWo, const float* __restrict__ cbo,
                       const float* __restrict__ dW1, const float* __restrict__ db1,
                       const float* __restrict__ dWo, const float* __restrict__ dbo,
                       float* __restrict__ out, int N, int G){
  __shared__ float feat[256];
  __shared__ float hid[128];
  __shared__ float red[2];
  int g = blockIdx.x;
  int t = threadIdx.x;   // 128
  int cnt = lbound(batch, N, g + 1) - lbound(batch, N, g);
  float sm = 0.f, mx = -FLT_MAX;
  for (int s = 0; s < PSLICES; ++s){
    sm += psum[(g*PSLICES+s)*HC + t];
    mx = fmaxf(mx, pmax[(g*PSLICES+s)*HC + t]);
  }
  float mean = sm / (float)((cnt > 1) ? cnt : 1);
  feat[t] = mean; feat[128 + t] = mx;
  float sq = mean*mean + mx*mx;
  for (int d = 32; d; d >>= 1) sq += __shfl_xor(sq, d);
  if ((t & 63) == 0) red[t >> 6] = sq;
  __syncthreads();
  float norm = sqrtf(red[0] + red[1]);
  float scale = 1.f / fmaxf(norm, 1e-12f);
  feat[t] *= scale; feat[128 + t] *= scale;
  __syncthreads();
  float hsum = cb1[t];
  for (int k = 0; k < 256; ++k) hsum += feat[k]*cW1[k*128 + t];
  hid[t] = fmaxf(hsum, 0.f);
  __syncthreads();
  if (t < 8){
    float o = cbo[t];
    for (int k = 0; k < 128; ++k) o += hid[k]*cWo[k*8 + t];
    out[g*8 + t] = o;
  }
  __syncthreads();
  float dsum = db1[t];
  for (int k = 0; k < 256; ++k) dsum += feat[k]*dW1[k*128 + t];
  hid[t] = fmaxf(dsum, 0.f);
  __syncthreads();
  if (t < 3){
    float o = dbo[t];
    for (int k = 0; k < 128; ++k) o += hid[k]*dWo[k*3 + t];
    out[G*8 + g*3 + t] = o;
  }
}

extern "C" void kernel_launch(void* const* d_in, const int* in_sizes, int n_in,
                              void* d_out, int out_size, void* d_ws, size_t ws_size,
                              hipStream_t stream) {
  const float* x     = (const float*)d_in[0];
  const int*   ei    = (const int*)  d_in[1];
  const int*   batch = (const int*)  d_in[2];
  const float* eW1 = (const float*)d_in[4];
  const float* eas1= (const float*)d_in[5];
  const float* ead1= (const float*)d_in[6];
  const float* eb1 = (const float*)d_in[7];
  const float* eW2 = (const float*)d_in[8];
  const float* eas2= (const float*)d_in[9];
  const float* ead2= (const float*)d_in[10];
  const float* eb2 = (const float*)d_in[11];
  const float* cW1 = (const float*)d_in[12];
  const float* cb1 = (const float*)d_in[13];
  const float* cWo = (const float*)d_in[14];
  const float* cbo = (const float*)d_in[15];
  const float* dW1 = (const float*)d_in[16];
  const float* db1 = (const float*)d_in[17];
  const float* dWo = (const float*)d_in[18];
  const float* dbo = (const float*)d_in[19];

  const int N = in_sizes[0] / 64;
  const int E = in_sizes[1] / 2;
  const int G = 64;
  const int T = E + N;

  char* ws = (char*)d_ws;
  size_t off = 0;
  auto alloc = [&](size_t bytes)->void* {
    void* p = ws + off; off += (bytes + 255) & ~(size_t)255; return p;
  };
  int*   rowptr = (int*)  alloc((size_t)(N+1)*4);
  int*   srcs   = (int*)  alloc((size_t)T*4);
  int*   pairs  = (int*)  alloc((size_t)T*4);
  int*   gmat   = (int*)  alloc((size_t)NBH*NBK*4);
  int*   coltot = (int*)  alloc((size_t)NBK*4);
  int*   bstart = (int*)  alloc((size_t)(NBK+1)*4);
  float* asrc   = (float*)alloc((size_t)N*NH*4);
  float* adst   = (float*)alloc((size_t)N*NH*4);
  unsigned short* bufH  = (unsigned short*)alloc((size_t)N*HC*2);  // bf16 gather matrix
  unsigned short* bufX2 = (unsigned short*)alloc((size_t)N*HC*2);  // bf16 layer-1 activations
  float* bufB   = (float*)alloc((size_t)N*HC*4);                   // f32 h2 (pooling input)
  float* psum   = (float*)alloc((size_t)G*PSLICES*HC*4);
  float* pmax   = (float*)alloc((size_t)G*PSLICES*HC*4);
  (void)ws_size; (void)n_in; (void)out_size;

  // ---- bucketed CSR build ----
  int chunk = (T + NBH - 1) / NBH;
  int nbuck = (N + (1 << BSHIFT) - 1) >> BSHIFT;      // 98
  k_hist   <<<NBH, 256, 0, stream>>>(ei, gmat, E, T, chunk);
  k_colscan<<<NBK, 256, 0, stream>>>(gmat, coltot);
  k_bstart <<<1,  NBK, 0, stream>>>(coltot, bstart, rowptr + N);
  k_bucket <<<NBH, 256, 0, stream>>>(ei, gmat, bstart, pairs, E, T, chunk);
  k_csr    <<<nbuck, 256, 0, stream>>>(pairs, bstart, rowptr, srcs, N);

  dim3 ggrid((N + 63) / 64, 2);
  // layer 1: X2 = relu(GAT(x) + b1)  (stored bf16)
  k_gemm_att<64,false><<<ggrid, 256, 0, stream>>>(x, eW1, eas1, ead1, bufH, asrc, adst, N);
  k_agg<true><<<(N+3)/4, 256, 0, stream>>>(bufH, asrc, adst, rowptr, srcs, eb1, bufX2, N, 1);
  // layer 2: h2 = GAT(X2) + b2  (f32 for pooling)
  k_gemm_att<128,true><<<ggrid, 256, 0, stream>>>(bufX2, eW2, eas2, ead2, bufH, asrc, adst, N);
  k_agg<false><<<(N+3)/4, 256, 0, stream>>>(bufH, asrc, adst, rowptr, srcs, eb2, bufB, N, 0);

  // pooling + heads (group bounds via binary search on sorted batch)
  k_pool_partial<<<G*PSLICES, 128, 0, stream>>>(bufB, batch, psum, pmax, N, G);
  k_head<<<G, 128, 0, stream>>>(psum, pmax, batch, cW1, cb1, cWo, cbo,
                                dW1, db1, dWo, dbo, (float*)d_out, N, G);
}